// Round 6
// baseline (806.576 us; speedup 1.0000x reference)
//
#include <hip/hip_runtime.h>
#include <hip/hip_bf16.h>

// ---------------------------------------------------------------------------
// MultiHopGATv2, fused formulation v4.
// Per layer:
//   gemm2_bf16 : xl = X@Wl+bl AND xr = X@Wr+br -> bf16 [N, H*C]
//                (RPT=32 rows/block, one 256-col slice per blockIdx.y)
//   node_fused : per dst node (1 wave), r3's branchless loop skeleton;
//                lrelu fold via two accumulators (abs = free modifier),
//                combined per-lane BEFORE the 16-lane reduce;
//                defer-max online softmax (wave-uniform rare slow path).
// CSR over dst (src values) built once per call.
// ---------------------------------------------------------------------------

__device__ __forceinline__ float bflo(unsigned w) { return __uint_as_float(w << 16); }
__device__ __forceinline__ float bfhi(unsigned w) { return __uint_as_float(w & 0xffff0000u); }
__device__ __forceinline__ unsigned short f2bf(float v) {
    unsigned u = __float_as_uint(v);
    u = (u + 0x7fff + ((u >> 16) & 1)) >> 16;   // round-to-nearest-even
    return (unsigned short)u;
}

// ---------------- CSR build ----------------

__global__ void zero_int_k(int* p, int n) {
    int i = blockIdx.x * 256 + threadIdx.x;
    if (i < n) p[i] = 0;
}

__global__ void count_k(const int* __restrict__ dst, int* __restrict__ cnt,
                        int E, int EP) {
    int e = blockIdx.x * 256 + threadIdx.x;
    if (e >= EP) return;
    int d = (e < E) ? dst[e] : (e - E);
    atomicAdd(&cnt[d], 1);
}

__global__ void scan1_k(const int* __restrict__ cnt, int* __restrict__ offs,
                        int* __restrict__ partial, int N) {
    __shared__ int buf[2][1024];
    int g = blockIdx.x * 1024 + threadIdx.x;
    int v = (g < N) ? cnt[g] : 0;
    int pi = 0;
    buf[0][threadIdx.x] = v;
    __syncthreads();
    for (int s = 1; s < 1024; s <<= 1) {
        int t = buf[pi][threadIdx.x];
        if ((int)threadIdx.x >= s) t += buf[pi][threadIdx.x - s];
        buf[pi ^ 1][threadIdx.x] = t;
        pi ^= 1;
        __syncthreads();
    }
    int incl = buf[pi][threadIdx.x];
    if (g < N) offs[g + 1] = incl;
    if (threadIdx.x == 1023) partial[blockIdx.x] = incl;
}

__global__ void scan2_k(int* partial, int nb) {
    if (blockIdx.x == 0 && threadIdx.x == 0) {
        int run = 0;
        for (int i = 0; i < nb; i++) { int t = partial[i]; partial[i] = run; run += t; }
    }
}

__global__ void scan3_k(int* __restrict__ offs, const int* __restrict__ partial, int N) {
    int g = blockIdx.x * 1024 + threadIdx.x;
    if (g < N) offs[g + 1] += partial[blockIdx.x];
    if (g == 0) offs[0] = 0;
}

__global__ void copy_int_k(const int* __restrict__ a, int* __restrict__ b, int n) {
    int i = blockIdx.x * 256 + threadIdx.x;
    if (i < n) b[i] = a[i];
}

__global__ void fill_k(const int* __restrict__ src, const int* __restrict__ dst,
                       int* __restrict__ cursor, int* __restrict__ csrc,
                       int E, int EP) {
    int e = blockIdx.x * 256 + threadIdx.x;
    if (e >= EP) return;
    int sv, d;
    if (e < E) { sv = src[e]; d = dst[e]; }
    else       { sv = e - E;  d = sv; }
    int p = atomicAdd(&cursor[d], 1);
    csrc[p] = sv;
}

// ---------------- fused dense transform ----------------
// 256 threads, RPT rows/block; blockIdx.y picks a 256-column slice of HCT.
template <int FIN>
__global__ void gemm2_bf16_k(const float* __restrict__ X,
                             const float* __restrict__ Wl, const float* __restrict__ bl,
                             const float* __restrict__ Wr, const float* __restrict__ br,
                             unsigned short* __restrict__ xl, unsigned short* __restrict__ xr,
                             int N, int HCT) {
    constexpr int RPT = 32;
    __shared__ float Xs[RPT][FIN];
    int tid  = threadIdx.x;
    int col  = blockIdx.y * 256 + tid;
    int row0 = blockIdx.x * RPT;
    for (int i = tid; i < RPT * FIN; i += 256) {
        int r = i / FIN, k = i % FIN;
        int gr = row0 + r;
        Xs[r][k] = (gr < N) ? X[(size_t)gr * FIN + k] : 0.f;
    }
    __syncthreads();
    float aL[RPT], aR[RPT];
    float b1 = bl[col], b2 = br[col];
#pragma unroll
    for (int r = 0; r < RPT; r++) { aL[r] = b1; aR[r] = b2; }
    for (int k = 0; k < FIN; k++) {
        float wl = Wl[(size_t)k * HCT + col];
        float wr = Wr[(size_t)k * HCT + col];
#pragma unroll
        for (int r = 0; r < RPT; r++) {
            float xv = Xs[r][k];
            aL[r] = fmaf(xv, wl, aL[r]);
            aR[r] = fmaf(xv, wr, aR[r]);
        }
    }
#pragma unroll
    for (int r = 0; r < RPT; r++) {
        int gr = row0 + r;
        if (gr < N) {
            xl[(size_t)gr * HCT + col] = f2bf(aL[r]);
            xr[(size_t)gr * HCT + col] = f2bf(aR[r]);
        }
    }
}

// ---------------- fused node pass v4 ----------------
// One wave per dst node. Lane l owns channels [l*F, l*F+F); head = l>>4.
template <int F, bool RELU>
__global__ void node_fused_k(const unsigned short* __restrict__ xl,
                             const unsigned short* __restrict__ xr,
                             const float* __restrict__ att, const float* __restrict__ bias,
                             const int* __restrict__ offs, const int* __restrict__ csrc,
                             float* __restrict__ out, int N) {
    constexpr int HCT = 64 * F;
    constexpr int NW  = F / 2;
    int wv   = blockIdx.x * 4 + (threadIdx.x >> 6);
    int lane = threadIdx.x & 63;
    if (wv >= N) return;

    float xrv[F], at[F];
    {
        const unsigned* xp = (const unsigned*)(xr + (size_t)wv * HCT + lane * F);
#pragma unroll
        for (int i = 0; i < NW; i++) {
            unsigned w = xp[i];
            xrv[2 * i] = bflo(w); xrv[2 * i + 1] = bfhi(w);
        }
#pragma unroll
        for (int i = 0; i < F; i++) at[i] = att[lane * F + i];
    }

    int o0 = offs[wv], o1 = offs[wv + 1];
    float m = -1e30f, s = 0.f;
    float acc[F];
#pragma unroll
    for (int i = 0; i < F; i++) acc[i] = 0.f;

    for (int j = o0; j < o1; ++j) {
        int sn = csrc[j];
        const unsigned* xp = (const unsigned*)(xl + (size_t)sn * HCT + lane * F);
        float xv[F];
#pragma unroll
        for (int i = 0; i < NW; i++) {
            unsigned w = xp[i];
            xv[2 * i] = bflo(w); xv[2 * i + 1] = bfhi(w);
        }
        float p1 = 0.f, p2 = 0.f;
#pragma unroll
        for (int i = 0; i < F; i++) {
            float a = xv[i] + xrv[i];
            p1 = fmaf(at[i], a, p1);            // sum att*a
            p2 = fmaf(at[i], fabsf(a), p2);     // sum att*|a|  (abs is free)
        }
        float p = fmaf(0.6f, p1, 0.4f * p2);    // lrelu fold, pre-reduce (linear)
        p += __shfl_xor(p, 1, 64);
        p += __shfl_xor(p, 2, 64);
        p += __shfl_xor(p, 4, 64);
        p += __shfl_xor(p, 8, 64);
        if (__any(p > m + 20.f)) {              // rare: raise running max
            float nm = fmaxf(m, p);
            float r  = __expf(m - nm);
            float w  = __expf(p - nm);
            s = fmaf(s, r, w);
#pragma unroll
            for (int i = 0; i < F; i++) acc[i] = fmaf(acc[i], r, w * xv[i]);
            m = nm;
        } else {                                 // common: w = exp(p-m) <= e^20
            float w = __expf(p - m);
            s += w;
#pragma unroll
            for (int i = 0; i < F; i++) acc[i] = fmaf(w, xv[i], acc[i]);
        }
    }

    float inv = 1.f / s;
#pragma unroll
    for (int i = 0; i < F; i++) acc[i] *= inv;
#pragma unroll
    for (int i = 0; i < F; i++) {               // sum the 4 heads
        acc[i] += __shfl_xor(acc[i], 16, 64);
        acc[i] += __shfl_xor(acc[i], 32, 64);
    }
    if (lane < 16) {
        float* op = out + (size_t)wv * (16 * F) + lane * F;
#pragma unroll
        for (int i = 0; i < F; i++) {
            float v = fmaf(acc[i], 0.25f, bias[lane * F + i]);
            if (RELU) v = fmaxf(v, 0.f);
            op[i] = v;
        }
    }
}

// ---------------------------------------------------------------------------

static inline size_t align256(size_t x) { return (x + 255) & ~(size_t)255; }

extern "C" void kernel_launch(void* const* d_in, const int* in_sizes, int n_in,
                              void* d_out, int out_size, void* d_ws, size_t ws_size,
                              hipStream_t stream) {
    const float* x  = (const float*)d_in[0];
    const int*   ei = (const int*)d_in[1];
    const int N  = in_sizes[0] / 9;
    const int E  = in_sizes[1] / 2;
    const int EP = E + N;
    const int* src = ei;
    const int* dst = ei + E;

    const float *Wl[3], *bl[3], *Wr[3], *br[3], *att[3], *bb[3];
    for (int i = 0; i < 3; i++) {
        Wl[i]  = (const float*)d_in[2 + 6 * i];
        bl[i]  = (const float*)d_in[3 + 6 * i];
        Wr[i]  = (const float*)d_in[4 + 6 * i];
        br[i]  = (const float*)d_in[5 + 6 * i];
        att[i] = (const float*)d_in[6 + 6 * i];
        bb[i]  = (const float*)d_in[7 + 6 * i];
    }

    // workspace layout (~119 MB)
    char* w = (char*)d_ws;
    unsigned short* xl = (unsigned short*)w; w += align256((size_t)N * 512 * 2);
    unsigned short* xr = (unsigned short*)w; w += align256((size_t)N * 512 * 2);
    float* hA = (float*)w;   w += align256((size_t)N * 64 * 4);
    float* hB = (float*)w;   w += align256((size_t)N * 64 * 4);
    int* offs   = (int*)w;   w += align256((size_t)(N + 1) * 4);
    int* cursor = (int*)w;   w += align256((size_t)N * 4);
    int* csrc   = (int*)w;   w += align256((size_t)EP * 4);
    int* partial = (int*)w;  w += 4096;

    // ---- CSR build over dst ----
    int* cnt = cursor;
    zero_int_k<<<(N + 255) / 256, 256, 0, stream>>>(cnt, N);
    count_k<<<(EP + 255) / 256, 256, 0, stream>>>(dst, cnt, E, EP);
    int nb = (N + 1023) / 1024;
    scan1_k<<<nb, 1024, 0, stream>>>(cnt, offs, partial, N);
    scan2_k<<<1, 64, 0, stream>>>(partial, nb);
    scan3_k<<<nb, 1024, 0, stream>>>(offs, partial, N);
    copy_int_k<<<(N + 255) / 256, 256, 0, stream>>>(offs, cursor, N);
    fill_k<<<(EP + 255) / 256, 256, 0, stream>>>(src, dst, cursor, csrc, E, EP);

    const int nodeBlocks = (N + 3) / 4;
    dim3 g1((N + 31) / 32, 1);   // HCT=256: one col slice
    dim3 g2((N + 31) / 32, 2);   // HCT=512: two col slices

    // ---- layer 0: 9 -> 64 (H*C = 256), relu ----
    gemm2_bf16_k<9><<<g1, 256, 0, stream>>>(
        x, Wl[0], bl[0], Wr[0], br[0], xl, xr, N, 256);
    node_fused_k<4, true><<<nodeBlocks, 256, 0, stream>>>(
        xl, xr, att[0], bb[0], offs, csrc, hA, N);

    // ---- layer 1: 64 -> 64 (H*C = 256), relu ----
    gemm2_bf16_k<64><<<g1, 256, 0, stream>>>(
        hA, Wl[1], bl[1], Wr[1], br[1], xl, xr, N, 256);
    node_fused_k<4, true><<<nodeBlocks, 256, 0, stream>>>(
        xl, xr, att[1], bb[1], offs, csrc, hB, N);

    // ---- layer 2: 64 -> 128 (H*C = 512), no relu ----
    gemm2_bf16_k<64><<<g2, 256, 0, stream>>>(
        hB, Wl[2], bl[2], Wr[2], br[2], xl, xr, N, 512);
    node_fused_k<8, false><<<nodeBlocks, 256, 0, stream>>>(
        xl, xr, att[2], bb[2], offs, csrc, (float*)d_out, N);
}

// Round 7
// 579.606 us; speedup vs baseline: 1.3916x; 1.3916x over previous
//
#include <hip/hip_runtime.h>
#include <hip/hip_bf16.h>

// ---------------------------------------------------------------------------
// MultiHopGATv2, fused formulation v5.
// Per layer:
//   gemm2_bf16 : xl = X@Wl+bl AND xr = X@Wr+br -> bf16 [N, H*C]
//                RPT=16 rows/block, CPT=1 (32 accumulators -> no spill),
//                one 256-col slice per blockIdx.y.
//   node_fused : per dst node (1 wave), branchless loop; lrelu fold via
//                two accumulators (abs = free VOP3 modifier) combined
//                per-lane BEFORE the 16-lane reduce; defer-max softmax.
// CSR over dst (src values) built once per call.
// ---------------------------------------------------------------------------

__device__ __forceinline__ float bflo(unsigned w) { return __uint_as_float(w << 16); }
__device__ __forceinline__ float bfhi(unsigned w) { return __uint_as_float(w & 0xffff0000u); }
__device__ __forceinline__ unsigned short f2bf(float v) {
    unsigned u = __float_as_uint(v);
    u = (u + 0x7fff + ((u >> 16) & 1)) >> 16;   // round-to-nearest-even
    return (unsigned short)u;
}

// ---------------- CSR build ----------------

__global__ void zero_int_k(int* p, int n) {
    int i = blockIdx.x * 256 + threadIdx.x;
    if (i < n) p[i] = 0;
}

__global__ void count_k(const int* __restrict__ dst, int* __restrict__ cnt,
                        int E, int EP) {
    int e = blockIdx.x * 256 + threadIdx.x;
    if (e >= EP) return;
    int d = (e < E) ? dst[e] : (e - E);
    atomicAdd(&cnt[d], 1);
}

__global__ void scan1_k(const int* __restrict__ cnt, int* __restrict__ offs,
                        int* __restrict__ partial, int N) {
    __shared__ int buf[2][1024];
    int g = blockIdx.x * 1024 + threadIdx.x;
    int v = (g < N) ? cnt[g] : 0;
    int pi = 0;
    buf[0][threadIdx.x] = v;
    __syncthreads();
    for (int s = 1; s < 1024; s <<= 1) {
        int t = buf[pi][threadIdx.x];
        if ((int)threadIdx.x >= s) t += buf[pi][threadIdx.x - s];
        buf[pi ^ 1][threadIdx.x] = t;
        pi ^= 1;
        __syncthreads();
    }
    int incl = buf[pi][threadIdx.x];
    if (g < N) offs[g + 1] = incl;
    if (threadIdx.x == 1023) partial[blockIdx.x] = incl;
}

__global__ void scan2_k(int* partial, int nb) {
    if (blockIdx.x == 0 && threadIdx.x == 0) {
        int run = 0;
        for (int i = 0; i < nb; i++) { int t = partial[i]; partial[i] = run; run += t; }
    }
}

__global__ void scan3_k(int* __restrict__ offs, const int* __restrict__ partial, int N) {
    int g = blockIdx.x * 1024 + threadIdx.x;
    if (g < N) offs[g + 1] += partial[blockIdx.x];
    if (g == 0) offs[0] = 0;
}

__global__ void copy_int_k(const int* __restrict__ a, int* __restrict__ b, int n) {
    int i = blockIdx.x * 256 + threadIdx.x;
    if (i < n) b[i] = a[i];
}

__global__ void fill_k(const int* __restrict__ src, const int* __restrict__ dst,
                       int* __restrict__ cursor, int* __restrict__ csrc,
                       int E, int EP) {
    int e = blockIdx.x * 256 + threadIdx.x;
    if (e >= EP) return;
    int sv, d;
    if (e < E) { sv = src[e]; d = dst[e]; }
    else       { sv = e - E;  d = sv; }
    int p = atomicAdd(&cursor[d], 1);
    csrc[p] = sv;
}

// ---------------- fused dense transform ----------------
// 256 threads, RPT=16 rows/block, blockIdx.y = 256-col slice of HCT.
// 32 fp32 accumulators per thread -> no register spill.
template <int FIN>
__global__ void gemm2_bf16_k(const float* __restrict__ X,
                             const float* __restrict__ Wl, const float* __restrict__ bl,
                             const float* __restrict__ Wr, const float* __restrict__ br,
                             unsigned short* __restrict__ xl, unsigned short* __restrict__ xr,
                             int N, int HCT) {
    constexpr int RPT = 16;
    __shared__ float Xs[RPT][FIN];
    int tid  = threadIdx.x;
    int col  = blockIdx.y * 256 + tid;
    int row0 = blockIdx.x * RPT;
    for (int i = tid; i < RPT * FIN; i += 256) {
        int r = i / FIN, k = i % FIN;
        int gr = row0 + r;
        Xs[r][k] = (gr < N) ? X[(size_t)gr * FIN + k] : 0.f;
    }
    __syncthreads();
    float aL[RPT], aR[RPT];
    float b1 = bl[col], b2 = br[col];
#pragma unroll
    for (int r = 0; r < RPT; r++) { aL[r] = b1; aR[r] = b2; }
    for (int k = 0; k < FIN; k++) {
        float wl = Wl[(size_t)k * HCT + col];
        float wr = Wr[(size_t)k * HCT + col];
#pragma unroll
        for (int r = 0; r < RPT; r++) {
            float xv = Xs[r][k];
            aL[r] = fmaf(xv, wl, aL[r]);
            aR[r] = fmaf(xv, wr, aR[r]);
        }
    }
#pragma unroll
    for (int r = 0; r < RPT; r++) {
        int gr = row0 + r;
        if (gr < N) {
            xl[(size_t)gr * HCT + col] = f2bf(aL[r]);
            xr[(size_t)gr * HCT + col] = f2bf(aR[r]);
        }
    }
}

// ---------------- fused node pass ----------------
// One wave per dst node. Lane l owns channels [l*F, l*F+F); head = l>>4.
template <int F, bool RELU>
__global__ void node_fused_k(const unsigned short* __restrict__ xl,
                             const unsigned short* __restrict__ xr,
                             const float* __restrict__ att, const float* __restrict__ bias,
                             const int* __restrict__ offs, const int* __restrict__ csrc,
                             float* __restrict__ out, int N) {
    constexpr int HCT = 64 * F;
    constexpr int NW  = F / 2;
    int wv   = blockIdx.x * 4 + (threadIdx.x >> 6);
    int lane = threadIdx.x & 63;
    if (wv >= N) return;

    float xrv[F], at[F];
    {
        const unsigned* xp = (const unsigned*)(xr + (size_t)wv * HCT + lane * F);
#pragma unroll
        for (int i = 0; i < NW; i++) {
            unsigned w = xp[i];
            xrv[2 * i] = bflo(w); xrv[2 * i + 1] = bfhi(w);
        }
#pragma unroll
        for (int i = 0; i < F; i++) at[i] = att[lane * F + i];
    }

    int o0 = offs[wv], o1 = offs[wv + 1];
    float m = -1e30f, s = 0.f;
    float acc[F];
#pragma unroll
    for (int i = 0; i < F; i++) acc[i] = 0.f;

    for (int j = o0; j < o1; ++j) {
        int sn = csrc[j];
        const unsigned* xp = (const unsigned*)(xl + (size_t)sn * HCT + lane * F);
        float xv[F];
#pragma unroll
        for (int i = 0; i < NW; i++) {
            unsigned w = xp[i];
            xv[2 * i] = bflo(w); xv[2 * i + 1] = bfhi(w);
        }
        float p1 = 0.f, p2 = 0.f;
#pragma unroll
        for (int i = 0; i < F; i++) {
            float a = xv[i] + xrv[i];
            p1 = fmaf(at[i], a, p1);            // sum att*a
            p2 = fmaf(at[i], fabsf(a), p2);     // sum att*|a|  (abs is free)
        }
        float p = fmaf(0.6f, p1, 0.4f * p2);    // lrelu fold, pre-reduce (linear)
        p += __shfl_xor(p, 1, 64);
        p += __shfl_xor(p, 2, 64);
        p += __shfl_xor(p, 4, 64);
        p += __shfl_xor(p, 8, 64);
        if (__any(p > m + 20.f)) {              // rare: raise running max
            float nm = fmaxf(m, p);
            float r  = __expf(m - nm);
            float w  = __expf(p - nm);
            s = fmaf(s, r, w);
#pragma unroll
            for (int i = 0; i < F; i++) acc[i] = fmaf(acc[i], r, w * xv[i]);
            m = nm;
        } else {                                 // common: w = exp(p-m) <= e^20
            float w = __expf(p - m);
            s += w;
#pragma unroll
            for (int i = 0; i < F; i++) acc[i] = fmaf(w, xv[i], acc[i]);
        }
    }

    float inv = 1.f / s;
#pragma unroll
    for (int i = 0; i < F; i++) acc[i] *= inv;
#pragma unroll
    for (int i = 0; i < F; i++) {               // sum the 4 heads
        acc[i] += __shfl_xor(acc[i], 16, 64);
        acc[i] += __shfl_xor(acc[i], 32, 64);
    }
    if (lane < 16) {
        float* op = out + (size_t)wv * (16 * F) + lane * F;
#pragma unroll
        for (int i = 0; i < F; i++) {
            float v = fmaf(acc[i], 0.25f, bias[lane * F + i]);
            if (RELU) v = fmaxf(v, 0.f);
            op[i] = v;
        }
    }
}

// ---------------------------------------------------------------------------

static inline size_t align256(size_t x) { return (x + 255) & ~(size_t)255; }

extern "C" void kernel_launch(void* const* d_in, const int* in_sizes, int n_in,
                              void* d_out, int out_size, void* d_ws, size_t ws_size,
                              hipStream_t stream) {
    const float* x  = (const float*)d_in[0];
    const int*   ei = (const int*)d_in[1];
    const int N  = in_sizes[0] / 9;
    const int E  = in_sizes[1] / 2;
    const int EP = E + N;
    const int* src = ei;
    const int* dst = ei + E;

    const float *Wl[3], *bl[3], *Wr[3], *br[3], *att[3], *bb[3];
    for (int i = 0; i < 3; i++) {
        Wl[i]  = (const float*)d_in[2 + 6 * i];
        bl[i]  = (const float*)d_in[3 + 6 * i];
        Wr[i]  = (const float*)d_in[4 + 6 * i];
        br[i]  = (const float*)d_in[5 + 6 * i];
        att[i] = (const float*)d_in[6 + 6 * i];
        bb[i]  = (const float*)d_in[7 + 6 * i];
    }

    // workspace layout (~119 MB)
    char* w = (char*)d_ws;
    unsigned short* xl = (unsigned short*)w; w += align256((size_t)N * 512 * 2);
    unsigned short* xr = (unsigned short*)w; w += align256((size_t)N * 512 * 2);
    float* hA = (float*)w;   w += align256((size_t)N * 64 * 4);
    float* hB = (float*)w;   w += align256((size_t)N * 64 * 4);
    int* offs   = (int*)w;   w += align256((size_t)(N + 1) * 4);
    int* cursor = (int*)w;   w += align256((size_t)N * 4);
    int* csrc   = (int*)w;   w += align256((size_t)EP * 4);
    int* partial = (int*)w;  w += 4096;

    // ---- CSR build over dst ----
    int* cnt = cursor;
    zero_int_k<<<(N + 255) / 256, 256, 0, stream>>>(cnt, N);
    count_k<<<(EP + 255) / 256, 256, 0, stream>>>(dst, cnt, E, EP);
    int nb = (N + 1023) / 1024;
    scan1_k<<<nb, 1024, 0, stream>>>(cnt, offs, partial, N);
    scan2_k<<<1, 64, 0, stream>>>(partial, nb);
    scan3_k<<<nb, 1024, 0, stream>>>(offs, partial, N);
    copy_int_k<<<(N + 255) / 256, 256, 0, stream>>>(offs, cursor, N);
    fill_k<<<(EP + 255) / 256, 256, 0, stream>>>(src, dst, cursor, csrc, E, EP);

    const int nodeBlocks = (N + 3) / 4;
    dim3 g1((N + 15) / 16, 1);   // HCT=256: one 256-col slice
    dim3 g2((N + 15) / 16, 2);   // HCT=512: two 256-col slices

    // ---- layer 0: 9 -> 64 (H*C = 256), relu ----
    gemm2_bf16_k<9><<<g1, 256, 0, stream>>>(
        x, Wl[0], bl[0], Wr[0], br[0], xl, xr, N, 256);
    node_fused_k<4, true><<<nodeBlocks, 256, 0, stream>>>(
        xl, xr, att[0], bb[0], offs, csrc, hA, N);

    // ---- layer 1: 64 -> 64 (H*C = 256), relu ----
    gemm2_bf16_k<64><<<g1, 256, 0, stream>>>(
        hA, Wl[1], bl[1], Wr[1], br[1], xl, xr, N, 256);
    node_fused_k<4, true><<<nodeBlocks, 256, 0, stream>>>(
        xl, xr, att[1], bb[1], offs, csrc, hB, N);

    // ---- layer 2: 64 -> 128 (H*C = 512), no relu ----
    gemm2_bf16_k<64><<<g2, 256, 0, stream>>>(
        hB, Wl[2], bl[2], Wr[2], br[2], xl, xr, N, 512);
    node_fused_k<8, false><<<nodeBlocks, 256, 0, stream>>>(
        xl, xr, att[2], bb[2], offs, csrc, (float*)d_out, N);
}

// Round 8
// 476.518 us; speedup vs baseline: 1.6926x; 1.2163x over previous
//
#include <hip/hip_runtime.h>
#include <hip/hip_bf16.h>

// ---------------------------------------------------------------------------
// MultiHopGATv2, fused formulation v6.
//   L0:  vector gemm (FIN=9, tiny) -> xl,xr bf16
//   L1/L2: split-precision bf16 MFMA gemm:
//          X@W ~= Xhi@Whi + Xlo@Whi + Xhi@Wlo   (rel err ~2^-16)
//          A row-major bf16 (16B frag loads), W packed in frag order (hi/lo),
//          bias preloaded into acc, LDS-transpose epilogue, bf16 out.
//   node_fused : per dst node (1 wave) online-softmax gather (unchanged).
// Buffer aliasing: Ahi/Alo live in dead hA/hB regions -> no extra workspace.
// ---------------------------------------------------------------------------

typedef __attribute__((ext_vector_type(8))) short bf16x8;
typedef __attribute__((ext_vector_type(4))) float f32x4;

__device__ __forceinline__ float bflo(unsigned w) { return __uint_as_float(w << 16); }
__device__ __forceinline__ float bfhi(unsigned w) { return __uint_as_float(w & 0xffff0000u); }
__device__ __forceinline__ unsigned short f2bf(float v) {
    unsigned u = __float_as_uint(v);
    u = (u + 0x7fff + ((u >> 16) & 1)) >> 16;   // round-to-nearest-even
    return (unsigned short)u;
}
__device__ __forceinline__ float bf2f(unsigned short h) {
    return __uint_as_float((unsigned)h << 16);
}

// ---------------- CSR build ----------------

__global__ void zero_int_k(int* p, int n) {
    int i = blockIdx.x * 256 + threadIdx.x;
    if (i < n) p[i] = 0;
}

__global__ void count_k(const int* __restrict__ dst, int* __restrict__ cnt,
                        int E, int EP) {
    int e = blockIdx.x * 256 + threadIdx.x;
    if (e >= EP) return;
    int d = (e < E) ? dst[e] : (e - E);
    atomicAdd(&cnt[d], 1);
}

__global__ void scan1_k(const int* __restrict__ cnt, int* __restrict__ offs,
                        int* __restrict__ partial, int N) {
    __shared__ int buf[2][1024];
    int g = blockIdx.x * 1024 + threadIdx.x;
    int v = (g < N) ? cnt[g] : 0;
    int pi = 0;
    buf[0][threadIdx.x] = v;
    __syncthreads();
    for (int s = 1; s < 1024; s <<= 1) {
        int t = buf[pi][threadIdx.x];
        if ((int)threadIdx.x >= s) t += buf[pi][threadIdx.x - s];
        buf[pi ^ 1][threadIdx.x] = t;
        pi ^= 1;
        __syncthreads();
    }
    int incl = buf[pi][threadIdx.x];
    if (g < N) offs[g + 1] = incl;
    if (threadIdx.x == 1023) partial[blockIdx.x] = incl;
}

__global__ void scan2_k(int* partial, int nb) {
    if (blockIdx.x == 0 && threadIdx.x == 0) {
        int run = 0;
        for (int i = 0; i < nb; i++) { int t = partial[i]; partial[i] = run; run += t; }
    }
}

__global__ void scan3_k(int* __restrict__ offs, const int* __restrict__ partial, int N) {
    int g = blockIdx.x * 1024 + threadIdx.x;
    if (g < N) offs[g + 1] += partial[blockIdx.x];
    if (g == 0) offs[0] = 0;
}

__global__ void copy_int_k(const int* __restrict__ a, int* __restrict__ b, int n) {
    int i = blockIdx.x * 256 + threadIdx.x;
    if (i < n) b[i] = a[i];
}

__global__ void fill_k(const int* __restrict__ src, const int* __restrict__ dst,
                       int* __restrict__ cursor, int* __restrict__ csrc,
                       int E, int EP) {
    int e = blockIdx.x * 256 + threadIdx.x;
    if (e >= EP) return;
    int sv, d;
    if (e < E) { sv = src[e]; d = dst[e]; }
    else       { sv = e - E;  d = sv; }
    int p = atomicAdd(&cursor[d], 1);
    csrc[p] = sv;
}

// ---------------- L0 vector gemm (FIN=9 only) ----------------
template <int FIN>
__global__ void gemm2_bf16_k(const float* __restrict__ X,
                             const float* __restrict__ Wl, const float* __restrict__ bl,
                             const float* __restrict__ Wr, const float* __restrict__ br,
                             unsigned short* __restrict__ xl, unsigned short* __restrict__ xr,
                             int N, int HCT) {
    constexpr int RPT = 16;
    __shared__ float Xs[RPT][FIN];
    int tid  = threadIdx.x;
    int col  = blockIdx.y * 256 + tid;
    int row0 = blockIdx.x * RPT;
    for (int i = tid; i < RPT * FIN; i += 256) {
        int r = i / FIN, k = i % FIN;
        int gr = row0 + r;
        Xs[r][k] = (gr < N) ? X[(size_t)gr * FIN + k] : 0.f;
    }
    __syncthreads();
    float aL[RPT], aR[RPT];
    float b1 = bl[col], b2 = br[col];
#pragma unroll
    for (int r = 0; r < RPT; r++) { aL[r] = b1; aR[r] = b2; }
    for (int k = 0; k < FIN; k++) {
        float wl = Wl[(size_t)k * HCT + col];
        float wr = Wr[(size_t)k * HCT + col];
#pragma unroll
        for (int r = 0; r < RPT; r++) {
            float xv = Xs[r][k];
            aL[r] = fmaf(xv, wl, aL[r]);
            aR[r] = fmaf(xv, wr, aR[r]);
        }
    }
#pragma unroll
    for (int r = 0; r < RPT; r++) {
        int gr = row0 + r;
        if (gr < N) {
            xl[(size_t)gr * HCT + col] = f2bf(aL[r]);
            xr[(size_t)gr * HCT + col] = f2bf(aR[r]);
        }
    }
}

// ---------------- split X -> hi/lo bf16 (row-major [N][64]) ----------------
__global__ void split_x_k(const float* __restrict__ X,
                          unsigned short* __restrict__ Ahi, unsigned short* __restrict__ Alo,
                          int total) {
    int i = blockIdx.x * 256 + threadIdx.x;
    if (i >= total) return;
    float v = X[i];
    unsigned short hi = f2bf(v);
    float lo = v - bf2f(hi);
    Ahi[i] = hi;
    Alo[i] = f2bf(lo);
}

// ---------------- pack W (both mats) into MFMA B-frag order, hi/lo ----------
// packed idx = ((ct*2 + ks)*64 + lane)*8 + j  ->  W[ks*32+(lane>>4)*8+j][ct*16+(lane&15)]
// ct spans [0, 2*HCT/16): first HCT/16 tiles = Wl cols, rest = Wr cols.
__global__ void split_w_k(const float* __restrict__ Wl, const float* __restrict__ Wr,
                          unsigned short* __restrict__ Whi, unsigned short* __restrict__ Wlo,
                          int HCT, int total) {
    int tid = blockIdx.x * 256 + threadIdx.x;
    if (tid >= total) return;
    int j  = tid & 7;
    int l  = (tid >> 3) & 63;
    int ks = (tid >> 9) & 1;
    int ct = tid >> 10;
    int k  = ks * 32 + (l >> 4) * 8 + j;
    int cg = ct * 16 + (l & 15);
    float v = (cg < HCT) ? Wl[(size_t)k * HCT + cg] : Wr[(size_t)k * HCT + (cg - HCT)];
    unsigned short hi = f2bf(v);
    Whi[tid] = hi;
    Wlo[tid] = f2bf(v - bf2f(hi));
}

// ---------------- MFMA gemm: [N x 64] @ [64 x HCT] x2 -> bf16 ----------------
// Block = 4 waves x 16 rows. K=64 = 2 mfma k-steps. CHUNKS = 2*HCT/128.
// Per chunk: 8 col-tiles x 6 mfma (hi*hi, lo*hi, hi*lo), LDS-transpose epilogue.
template <int CHUNKS>
__global__ void mfma_gemm_k(const unsigned short* __restrict__ Ahi,
                            const unsigned short* __restrict__ Alo,
                            const unsigned short* __restrict__ Wphi,
                            const unsigned short* __restrict__ Wplo,
                            const float* __restrict__ bl, const float* __restrict__ br,
                            unsigned short* __restrict__ xl, unsigned short* __restrict__ xr,
                            int N, int HCT) {
    __shared__ float lds[4][16][128];
    int tid = threadIdx.x;
    int w   = tid >> 6, l = tid & 63;
    int l15 = l & 15,  seg = l >> 4;
    int row  = blockIdx.x * 64 + w * 16 + l15;
    int arow = (row < N) ? row : (N - 1);

    bf16x8 a0h = *(const bf16x8*)(Ahi + (size_t)arow * 64 + seg * 8);
    bf16x8 a1h = *(const bf16x8*)(Ahi + (size_t)arow * 64 + 32 + seg * 8);
    bf16x8 a0l = *(const bf16x8*)(Alo + (size_t)arow * 64 + seg * 8);
    bf16x8 a1l = *(const bf16x8*)(Alo + (size_t)arow * 64 + 32 + seg * 8);

    for (int c = 0; c < CHUNKS; c++) {
        int mat   = (c * 128) / HCT;
        int mcol0 = (c * 128) % HCT;
        const float* bias = mat ? br : bl;
        unsigned short* out = mat ? xr : xl;
        f32x4 acc[8];
#pragma unroll
        for (int t = 0; t < 8; t++) {
            float bv = bias[mcol0 + t * 16 + l15];
            acc[t] = (f32x4){bv, bv, bv, bv};
        }
#pragma unroll
        for (int t = 0; t < 8; t++) {
            size_t ct = (size_t)(c * 8 + t);
            bf16x8 b0h = *(const bf16x8*)(Wphi + ((ct * 2    ) * 64 + l) * 8);
            bf16x8 b1h = *(const bf16x8*)(Wphi + ((ct * 2 + 1) * 64 + l) * 8);
            bf16x8 b0l = *(const bf16x8*)(Wplo + ((ct * 2    ) * 64 + l) * 8);
            bf16x8 b1l = *(const bf16x8*)(Wplo + ((ct * 2 + 1) * 64 + l) * 8);
            acc[t] = __builtin_amdgcn_mfma_f32_16x16x32_bf16(a0h, b0h, acc[t], 0, 0, 0);
            acc[t] = __builtin_amdgcn_mfma_f32_16x16x32_bf16(a1h, b1h, acc[t], 0, 0, 0);
            acc[t] = __builtin_amdgcn_mfma_f32_16x16x32_bf16(a0l, b0h, acc[t], 0, 0, 0);
            acc[t] = __builtin_amdgcn_mfma_f32_16x16x32_bf16(a1l, b1h, acc[t], 0, 0, 0);
            acc[t] = __builtin_amdgcn_mfma_f32_16x16x32_bf16(a0h, b0l, acc[t], 0, 0, 0);
            acc[t] = __builtin_amdgcn_mfma_f32_16x16x32_bf16(a1h, b1l, acc[t], 0, 0, 0);
        }
        // epilogue: D lane mapping col=lane&15, row=(lane>>4)*4+reg (m89-verified)
#pragma unroll
        for (int t = 0; t < 8; t++)
#pragma unroll
            for (int r = 0; r < 4; r++)
                lds[w][seg * 4 + r][t * 16 + l15] = acc[t][r];
        // wave-private region; compiler inserts lgkmcnt for the RAW dependency
#pragma unroll
        for (int r = 0; r < 16; r++) {
            int orow = blockIdx.x * 64 + w * 16 + r;
            if (orow < N) {
                float v0 = lds[w][r][2 * l];
                float v1 = lds[w][r][2 * l + 1];
                unsigned pack = (unsigned)f2bf(v0) | ((unsigned)f2bf(v1) << 16);
                *(unsigned*)(out + (size_t)orow * HCT + mcol0 + 2 * l) = pack;
            }
        }
    }
}

// ---------------- fused node pass (unchanged from r7) ----------------
template <int F, bool RELU>
__global__ void node_fused_k(const unsigned short* __restrict__ xl,
                             const unsigned short* __restrict__ xr,
                             const float* __restrict__ att, const float* __restrict__ bias,
                             const int* __restrict__ offs, const int* __restrict__ csrc,
                             float* __restrict__ out, int N) {
    constexpr int HCT = 64 * F;
    constexpr int NW  = F / 2;
    int wv   = blockIdx.x * 4 + (threadIdx.x >> 6);
    int lane = threadIdx.x & 63;
    if (wv >= N) return;

    float xrv[F], at[F];
    {
        const unsigned* xp = (const unsigned*)(xr + (size_t)wv * HCT + lane * F);
#pragma unroll
        for (int i = 0; i < NW; i++) {
            unsigned w = xp[i];
            xrv[2 * i] = bflo(w); xrv[2 * i + 1] = bfhi(w);
        }
#pragma unroll
        for (int i = 0; i < F; i++) at[i] = att[lane * F + i];
    }

    int o0 = offs[wv], o1 = offs[wv + 1];
    float m = -1e30f, s = 0.f;
    float acc[F];
#pragma unroll
    for (int i = 0; i < F; i++) acc[i] = 0.f;

    for (int j = o0; j < o1; ++j) {
        int sn = csrc[j];
        const unsigned* xp = (const unsigned*)(xl + (size_t)sn * HCT + lane * F);
        float xv[F];
#pragma unroll
        for (int i = 0; i < NW; i++) {
            unsigned w = xp[i];
            xv[2 * i] = bflo(w); xv[2 * i + 1] = bfhi(w);
        }
        float p1 = 0.f, p2 = 0.f;
#pragma unroll
        for (int i = 0; i < F; i++) {
            float a = xv[i] + xrv[i];
            p1 = fmaf(at[i], a, p1);
            p2 = fmaf(at[i], fabsf(a), p2);
        }
        float p = fmaf(0.6f, p1, 0.4f * p2);
        p += __shfl_xor(p, 1, 64);
        p += __shfl_xor(p, 2, 64);
        p += __shfl_xor(p, 4, 64);
        p += __shfl_xor(p, 8, 64);
        if (__any(p > m + 20.f)) {
            float nm = fmaxf(m, p);
            float r  = __expf(m - nm);
            float w  = __expf(p - nm);
            s = fmaf(s, r, w);
#pragma unroll
            for (int i = 0; i < F; i++) acc[i] = fmaf(acc[i], r, w * xv[i]);
            m = nm;
        } else {
            float w = __expf(p - m);
            s += w;
#pragma unroll
            for (int i = 0; i < F; i++) acc[i] = fmaf(w, xv[i], acc[i]);
        }
    }

    float inv = 1.f / s;
#pragma unroll
    for (int i = 0; i < F; i++) acc[i] *= inv;
#pragma unroll
    for (int i = 0; i < F; i++) {
        acc[i] += __shfl_xor(acc[i], 16, 64);
        acc[i] += __shfl_xor(acc[i], 32, 64);
    }
    if (lane < 16) {
        float* op = out + (size_t)wv * (16 * F) + lane * F;
#pragma unroll
        for (int i = 0; i < F; i++) {
            float v = fmaf(acc[i], 0.25f, bias[lane * F + i]);
            if (RELU) v = fmaxf(v, 0.f);
            op[i] = v;
        }
    }
}

// ---------------------------------------------------------------------------

static inline size_t align256(size_t x) { return (x + 255) & ~(size_t)255; }

extern "C" void kernel_launch(void* const* d_in, const int* in_sizes, int n_in,
                              void* d_out, int out_size, void* d_ws, size_t ws_size,
                              hipStream_t stream) {
    const float* x  = (const float*)d_in[0];
    const int*   ei = (const int*)d_in[1];
    const int N  = in_sizes[0] / 9;
    const int E  = in_sizes[1] / 2;
    const int EP = E + N;
    const int* src = ei;
    const int* dst = ei + E;

    const float *Wl[3], *bl[3], *Wr[3], *br[3], *att[3], *bb[3];
    for (int i = 0; i < 3; i++) {
        Wl[i]  = (const float*)d_in[2 + 6 * i];
        bl[i]  = (const float*)d_in[3 + 6 * i];
        Wr[i]  = (const float*)d_in[4 + 6 * i];
        br[i]  = (const float*)d_in[5 + 6 * i];
        att[i] = (const float*)d_in[6 + 6 * i];
        bb[i]  = (const float*)d_in[7 + 6 * i];
    }

    // workspace layout (~120 MB)
    char* w = (char*)d_ws;
    unsigned short* xl = (unsigned short*)w; w += align256((size_t)N * 512 * 2);
    unsigned short* xr = (unsigned short*)w; w += align256((size_t)N * 512 * 2);
    float* hA = (float*)w;   w += align256((size_t)N * 64 * 4);   // also Ahi2/Alo2
    float* hB = (float*)w;   w += align256((size_t)N * 64 * 4);   // also Ahi1/Alo1
    int* offs   = (int*)w;   w += align256((size_t)(N + 1) * 4);
    int* cursor = (int*)w;   w += align256((size_t)N * 4);
    int* csrc   = (int*)w;   w += align256((size_t)EP * 4);
    int* partial = (int*)w;  w += 4096;
    unsigned short* Wp1h = (unsigned short*)w; w += align256((size_t)32 * 1024 * 2);
    unsigned short* Wp1l = (unsigned short*)w; w += align256((size_t)32 * 1024 * 2);
    unsigned short* Wp2h = (unsigned short*)w; w += align256((size_t)64 * 1024 * 2);
    unsigned short* Wp2l = (unsigned short*)w; w += align256((size_t)64 * 1024 * 2);

    // aliases: Ahi/Alo buffers live in dead hA/hB regions (each 12.8MB = 2x6.4MB)
    unsigned short* Ahi1 = (unsigned short*)hB;               // from hA, used by L1 gemm
    unsigned short* Alo1 = Ahi1 + (size_t)N * 64;
    unsigned short* Ahi2 = (unsigned short*)hA;               // from hB, used by L2 gemm
    unsigned short* Alo2 = Ahi2 + (size_t)N * 64;

    // ---- CSR build over dst ----
    int* cnt = cursor;
    zero_int_k<<<(N + 255) / 256, 256, 0, stream>>>(cnt, N);
    count_k<<<(EP + 255) / 256, 256, 0, stream>>>(dst, cnt, E, EP);
    int nb = (N + 1023) / 1024;
    scan1_k<<<nb, 1024, 0, stream>>>(cnt, offs, partial, N);
    scan2_k<<<1, 64, 0, stream>>>(partial, nb);
    scan3_k<<<nb, 1024, 0, stream>>>(offs, partial, N);
    copy_int_k<<<(N + 255) / 256, 256, 0, stream>>>(offs, cursor, N);
    fill_k<<<(EP + 255) / 256, 256, 0, stream>>>(src, dst, cursor, csrc, E, EP);

    // ---- pack weights for L1/L2 (once per call) ----
    split_w_k<<<(32 * 1024 + 255) / 256, 256, 0, stream>>>(Wl[1], Wr[1], Wp1h, Wp1l, 256, 32 * 1024);
    split_w_k<<<(64 * 1024 + 255) / 256, 256, 0, stream>>>(Wl[2], Wr[2], Wp2h, Wp2l, 512, 64 * 1024);

    const int nodeBlocks = (N + 3) / 4;
    const int gemmBlocks = (N + 63) / 64;
    const int splitBlocks = (N * 64 + 255) / 256;

    // ---- layer 0: 9 -> 64 (H*C = 256), vector gemm, relu ----
    dim3 g1((N + 15) / 16, 1);
    gemm2_bf16_k<9><<<g1, 256, 0, stream>>>(
        x, Wl[0], bl[0], Wr[0], br[0], xl, xr, N, 256);
    node_fused_k<4, true><<<nodeBlocks, 256, 0, stream>>>(
        xl, xr, att[0], bb[0], offs, csrc, hA, N);

    // ---- layer 1: 64 -> 64 (H*C = 256), MFMA gemm, relu ----
    split_x_k<<<splitBlocks, 256, 0, stream>>>(hA, Ahi1, Alo1, N * 64);
    mfma_gemm_k<4><<<gemmBlocks, 256, 0, stream>>>(
        Ahi1, Alo1, Wp1h, Wp1l, bl[1], br[1], xl, xr, N, 256);
    node_fused_k<4, true><<<nodeBlocks, 256, 0, stream>>>(
        xl, xr, att[1], bb[1], offs, csrc, hB, N);

    // ---- layer 2: 64 -> 128 (H*C = 512), MFMA gemm, no relu ----
    split_x_k<<<splitBlocks, 256, 0, stream>>>(hB, Ahi2, Alo2, N * 64);
    mfma_gemm_k<8><<<gemmBlocks, 256, 0, stream>>>(
        Ahi2, Alo2, Wp2h, Wp2l, bl[2], br[2], xl, xr, N, 512);
    node_fused_k<8, false><<<nodeBlocks, 256, 0, stream>>>(
        xl, xr, att[2], bb[2], offs, csrc, (float*)d_out, N);
}

// Round 9
// 465.809 us; speedup vs baseline: 1.7316x; 1.0230x over previous
//
#include <hip/hip_runtime.h>
#include <hip/hip_bf16.h>

// ---------------------------------------------------------------------------
// MultiHopGATv2, fused formulation v7.
//   L0: node_l0_k — GEMM fused into the node pass. Lane preloads its 4 Wl
//       columns (fp32); per edge, xl[src] computed on the fly from the
//       9-float x row (wave-uniform broadcast loads, 36B/edge). Exact fp32.
//       Writes hi/lo bf16 split of relu(out) for the L1 MFMA GEMM.
//   L1/L2: split-precision bf16 MFMA gemm (Xhi@Whi + Xlo@Whi + Xhi@Wlo),
//       node_fused_k writes hi/lo split (L1) or fp32 d_out (L2).
//   CSR: zero(2N) -> count -> 3-step scan -> fill (offs + atomic cnt2).
// 12 dispatches total.
// ---------------------------------------------------------------------------

typedef __attribute__((ext_vector_type(8))) short bf16x8;
typedef __attribute__((ext_vector_type(4))) float f32x4;

__device__ __forceinline__ float bflo(unsigned w) { return __uint_as_float(w << 16); }
__device__ __forceinline__ float bfhi(unsigned w) { return __uint_as_float(w & 0xffff0000u); }
__device__ __forceinline__ unsigned short f2bf(float v) {
    unsigned u = __float_as_uint(v);
    u = (u + 0x7fff + ((u >> 16) & 1)) >> 16;   // round-to-nearest-even
    return (unsigned short)u;
}
__device__ __forceinline__ float bf2f(unsigned short h) {
    return __uint_as_float((unsigned)h << 16);
}

// ---------------- CSR build ----------------

__global__ void zero_int_k(int* p, int n) {
    int i = blockIdx.x * 256 + threadIdx.x;
    if (i < n) p[i] = 0;
}

__global__ void count_k(const int* __restrict__ dst, int* __restrict__ cnt,
                        int E, int EP) {
    int e = blockIdx.x * 256 + threadIdx.x;
    if (e >= EP) return;
    int d = (e < E) ? dst[e] : (e - E);
    atomicAdd(&cnt[d], 1);
}

__global__ void scan1_k(const int* __restrict__ cnt, int* __restrict__ offs,
                        int* __restrict__ partial, int N) {
    __shared__ int buf[2][1024];
    int g = blockIdx.x * 1024 + threadIdx.x;
    int v = (g < N) ? cnt[g] : 0;
    int pi = 0;
    buf[0][threadIdx.x] = v;
    __syncthreads();
    for (int s = 1; s < 1024; s <<= 1) {
        int t = buf[pi][threadIdx.x];
        if ((int)threadIdx.x >= s) t += buf[pi][threadIdx.x - s];
        buf[pi ^ 1][threadIdx.x] = t;
        pi ^= 1;
        __syncthreads();
    }
    int incl = buf[pi][threadIdx.x];
    if (g < N) offs[g + 1] = incl;
    if (threadIdx.x == 1023) partial[blockIdx.x] = incl;
}

__global__ void scan2_k(int* partial, int nb) {
    if (blockIdx.x == 0 && threadIdx.x == 0) {
        int run = 0;
        for (int i = 0; i < nb; i++) { int t = partial[i]; partial[i] = run; run += t; }
    }
}

__global__ void scan3_k(int* __restrict__ offs, const int* __restrict__ partial, int N) {
    int g = blockIdx.x * 1024 + threadIdx.x;
    if (g < N) offs[g + 1] += partial[blockIdx.x];
    if (g == 0) offs[0] = 0;
}

__global__ void fill2_k(const int* __restrict__ src, const int* __restrict__ dst,
                        const int* __restrict__ offs, int* __restrict__ cnt2,
                        int* __restrict__ csrc, int E, int EP) {
    int e = blockIdx.x * 256 + threadIdx.x;
    if (e >= EP) return;
    int sv, d;
    if (e < E) { sv = src[e]; d = dst[e]; }
    else       { sv = e - E;  d = sv; }
    int p = offs[d] + atomicAdd(&cnt2[d], 1);
    csrc[p] = sv;
}

// ---------------- pack W (L1 and L2) into MFMA B-frag order, hi/lo ----------
__device__ __forceinline__ void pack_one(const float* Wl, const float* Wr,
                                         unsigned short* Wh, unsigned short* Wlo,
                                         int HCT, int t) {
    int j  = t & 7;
    int l  = (t >> 3) & 63;
    int ks = (t >> 9) & 1;
    int ct = t >> 10;
    int k  = ks * 32 + (l >> 4) * 8 + j;
    int cg = ct * 16 + (l & 15);
    float v = (cg < HCT) ? Wl[(size_t)k * HCT + cg] : Wr[(size_t)k * HCT + (cg - HCT)];
    unsigned short hi = f2bf(v);
    Wh[t]  = hi;
    Wlo[t] = f2bf(v - bf2f(hi));
}

__global__ void split_w2_k(const float* __restrict__ Wl1, const float* __restrict__ Wr1,
                           unsigned short* __restrict__ W1h, unsigned short* __restrict__ W1l,
                           const float* __restrict__ Wl2, const float* __restrict__ Wr2,
                           unsigned short* __restrict__ W2h, unsigned short* __restrict__ W2l) {
    int tid = blockIdx.x * 256 + threadIdx.x;
    if (tid < 32 * 1024) pack_one(Wl1, Wr1, W1h, W1l, 256, tid);
    else                 pack_one(Wl2, Wr2, W2h, W2l, 512, tid - 32 * 1024);
}

// ---------------- MFMA gemm: [N x 64] @ [64 x HCT] x2 -> bf16 ----------------
template <int CHUNKS>
__global__ void mfma_gemm_k(const unsigned short* __restrict__ Ahi,
                            const unsigned short* __restrict__ Alo,
                            const unsigned short* __restrict__ Wphi,
                            const unsigned short* __restrict__ Wplo,
                            const float* __restrict__ bl, const float* __restrict__ br,
                            unsigned short* __restrict__ xl, unsigned short* __restrict__ xr,
                            int N, int HCT) {
    __shared__ float lds[4][16][128];
    int tid = threadIdx.x;
    int w   = tid >> 6, l = tid & 63;
    int l15 = l & 15,  seg = l >> 4;
    int row  = blockIdx.x * 64 + w * 16 + l15;
    int arow = (row < N) ? row : (N - 1);

    bf16x8 a0h = *(const bf16x8*)(Ahi + (size_t)arow * 64 + seg * 8);
    bf16x8 a1h = *(const bf16x8*)(Ahi + (size_t)arow * 64 + 32 + seg * 8);
    bf16x8 a0l = *(const bf16x8*)(Alo + (size_t)arow * 64 + seg * 8);
    bf16x8 a1l = *(const bf16x8*)(Alo + (size_t)arow * 64 + 32 + seg * 8);

    for (int c = 0; c < CHUNKS; c++) {
        int mat   = (c * 128) / HCT;
        int mcol0 = (c * 128) % HCT;
        const float* bias = mat ? br : bl;
        unsigned short* out = mat ? xr : xl;
        f32x4 acc[8];
#pragma unroll
        for (int t = 0; t < 8; t++) {
            float bv = bias[mcol0 + t * 16 + l15];
            acc[t] = (f32x4){bv, bv, bv, bv};
        }
#pragma unroll
        for (int t = 0; t < 8; t++) {
            size_t ct = (size_t)(c * 8 + t);
            bf16x8 b0h = *(const bf16x8*)(Wphi + ((ct * 2    ) * 64 + l) * 8);
            bf16x8 b1h = *(const bf16x8*)(Wphi + ((ct * 2 + 1) * 64 + l) * 8);
            bf16x8 b0l = *(const bf16x8*)(Wplo + ((ct * 2    ) * 64 + l) * 8);
            bf16x8 b1l = *(const bf16x8*)(Wplo + ((ct * 2 + 1) * 64 + l) * 8);
            acc[t] = __builtin_amdgcn_mfma_f32_16x16x32_bf16(a0h, b0h, acc[t], 0, 0, 0);
            acc[t] = __builtin_amdgcn_mfma_f32_16x16x32_bf16(a1h, b1h, acc[t], 0, 0, 0);
            acc[t] = __builtin_amdgcn_mfma_f32_16x16x32_bf16(a0l, b0h, acc[t], 0, 0, 0);
            acc[t] = __builtin_amdgcn_mfma_f32_16x16x32_bf16(a1l, b1h, acc[t], 0, 0, 0);
            acc[t] = __builtin_amdgcn_mfma_f32_16x16x32_bf16(a0h, b0l, acc[t], 0, 0, 0);
            acc[t] = __builtin_amdgcn_mfma_f32_16x16x32_bf16(a1h, b1l, acc[t], 0, 0, 0);
        }
#pragma unroll
        for (int t = 0; t < 8; t++)
#pragma unroll
            for (int r = 0; r < 4; r++)
                lds[w][seg * 4 + r][t * 16 + l15] = acc[t][r];
#pragma unroll
        for (int r = 0; r < 16; r++) {
            int orow = blockIdx.x * 64 + w * 16 + r;
            if (orow < N) {
                float v0 = lds[w][r][2 * l];
                float v1 = lds[w][r][2 * l + 1];
                unsigned pack = (unsigned)f2bf(v0) | ((unsigned)f2bf(v1) << 16);
                *(unsigned*)(out + (size_t)orow * HCT + mcol0 + 2 * l) = pack;
            }
        }
    }
}

// ---------------- layer-0 fully fused node pass (fp32 exact) ----------------
// One wave per dst node. Lane owns 4 channels of 256; head = lane>>4.
// xl[src] computed on the fly: 9-float x row (wave-uniform loads) x preloaded
// Wl columns. xr computed once per node. Writes relu(mean_heads+bias) as
// hi/lo bf16 split for the L1 MFMA gemm.
__global__ void node_l0_k(const float* __restrict__ X,
                          const float* __restrict__ Wl, const float* __restrict__ bl,
                          const float* __restrict__ Wr, const float* __restrict__ br,
                          const float* __restrict__ att, const float* __restrict__ bias,
                          const int* __restrict__ offs, const int* __restrict__ csrc,
                          unsigned short* __restrict__ Yhi, unsigned short* __restrict__ Ylo,
                          int N) {
    int wv   = blockIdx.x * 4 + (threadIdx.x >> 6);
    int lane = threadIdx.x & 63;
    if (wv >= N) return;
    int c0 = lane * 4;

    float at[4];
#pragma unroll
    for (int i = 0; i < 4; i++) at[i] = att[c0 + i];

    // per-node xr row (fp32)
    float xrv[4];
    {
        float xsd[9];
#pragma unroll
        for (int k = 0; k < 9; k++) xsd[k] = X[(size_t)wv * 9 + k];
#pragma unroll
        for (int i = 0; i < 4; i++) xrv[i] = br[c0 + i];
#pragma unroll
        for (int k = 0; k < 9; k++)
#pragma unroll
            for (int i = 0; i < 4; i++)
                xrv[i] = fmaf(xsd[k], Wr[k * 256 + c0 + i], xrv[i]);
    }

    // preload Wl columns + bias (36 + 4 regs)
    float wl[9][4], blv[4];
#pragma unroll
    for (int k = 0; k < 9; k++) {
        f32x4 wv4 = *(const f32x4*)(Wl + k * 256 + c0);
#pragma unroll
        for (int i = 0; i < 4; i++) wl[k][i] = wv4[i];
    }
#pragma unroll
    for (int i = 0; i < 4; i++) blv[i] = bl[c0 + i];

    int o0 = offs[wv], o1 = offs[wv + 1];
    float m = -1e30f, s = 0.f;
    float acc[4] = {0.f, 0.f, 0.f, 0.f};

    for (int j = o0; j < o1; ++j) {
        int sn = csrc[j];
        const float* xp = X + (size_t)sn * 9;
        float xs[9];
#pragma unroll
        for (int k = 0; k < 9; k++) xs[k] = xp[k];   // wave-uniform broadcast
        float xv[4] = {blv[0], blv[1], blv[2], blv[3]};
#pragma unroll
        for (int k = 0; k < 9; k++)
#pragma unroll
            for (int i = 0; i < 4; i++) xv[i] = fmaf(xs[k], wl[k][i], xv[i]);
        float p1 = 0.f, p2 = 0.f;
#pragma unroll
        for (int i = 0; i < 4; i++) {
            float a = xv[i] + xrv[i];
            p1 = fmaf(at[i], a, p1);
            p2 = fmaf(at[i], fabsf(a), p2);
        }
        float p = fmaf(0.6f, p1, 0.4f * p2);
        p += __shfl_xor(p, 1, 64);
        p += __shfl_xor(p, 2, 64);
        p += __shfl_xor(p, 4, 64);
        p += __shfl_xor(p, 8, 64);
        if (__any(p > m + 20.f)) {
            float nm = fmaxf(m, p);
            float r  = __expf(m - nm);
            float w  = __expf(p - nm);
            s = fmaf(s, r, w);
#pragma unroll
            for (int i = 0; i < 4; i++) acc[i] = fmaf(acc[i], r, w * xv[i]);
            m = nm;
        } else {
            float w = __expf(p - m);
            s += w;
#pragma unroll
            for (int i = 0; i < 4; i++) acc[i] = fmaf(w, xv[i], acc[i]);
        }
    }

    float inv = 1.f / s;
#pragma unroll
    for (int i = 0; i < 4; i++) acc[i] *= inv;
#pragma unroll
    for (int i = 0; i < 4; i++) {
        acc[i] += __shfl_xor(acc[i], 16, 64);
        acc[i] += __shfl_xor(acc[i], 32, 64);
    }
    if (lane < 16) {
        unsigned short h[4], lo[4];
#pragma unroll
        for (int i = 0; i < 4; i++) {
            float v = fmaf(acc[i], 0.25f, bias[lane * 4 + i]);
            v = fmaxf(v, 0.f);
            h[i] = f2bf(v);
            lo[i] = f2bf(v - bf2f(h[i]));
        }
        size_t base = (size_t)wv * 64 + lane * 4;
        *(uint2*)(Yhi + base) = (uint2){(unsigned)h[0] | ((unsigned)h[1] << 16),
                                        (unsigned)h[2] | ((unsigned)h[3] << 16)};
        *(uint2*)(Ylo + base) = (uint2){(unsigned)lo[0] | ((unsigned)lo[1] << 16),
                                        (unsigned)lo[2] | ((unsigned)lo[3] << 16)};
    }
}

// ---------------- fused node pass (L1/L2) ----------------
// OUT=0: write relu(res) as hi/lo bf16 split [N,16F]  (feeds next MFMA gemm)
// OUT=1: write res as fp32 [N,16F] (final output, no relu)
template <int F, int OUT>
__global__ void node_fused_k(const unsigned short* __restrict__ xl,
                             const unsigned short* __restrict__ xr,
                             const float* __restrict__ att, const float* __restrict__ bias,
                             const int* __restrict__ offs, const int* __restrict__ csrc,
                             unsigned short* __restrict__ Yhi, unsigned short* __restrict__ Ylo,
                             float* __restrict__ out, int N) {
    constexpr int HCT = 64 * F;
    constexpr int NW  = F / 2;
    int wv   = blockIdx.x * 4 + (threadIdx.x >> 6);
    int lane = threadIdx.x & 63;
    if (wv >= N) return;

    float xrv[F], at[F];
    {
        const unsigned* xp = (const unsigned*)(xr + (size_t)wv * HCT + lane * F);
#pragma unroll
        for (int i = 0; i < NW; i++) {
            unsigned w = xp[i];
            xrv[2 * i] = bflo(w); xrv[2 * i + 1] = bfhi(w);
        }
#pragma unroll
        for (int i = 0; i < F; i++) at[i] = att[lane * F + i];
    }

    int o0 = offs[wv], o1 = offs[wv + 1];
    float m = -1e30f, s = 0.f;
    float acc[F];
#pragma unroll
    for (int i = 0; i < F; i++) acc[i] = 0.f;

    for (int j = o0; j < o1; ++j) {
        int sn = csrc[j];
        const unsigned* xp = (const unsigned*)(xl + (size_t)sn * HCT + lane * F);
        float xv[F];
#pragma unroll
        for (int i = 0; i < NW; i++) {
            unsigned w = xp[i];
            xv[2 * i] = bflo(w); xv[2 * i + 1] = bfhi(w);
        }
        float p1 = 0.f, p2 = 0.f;
#pragma unroll
        for (int i = 0; i < F; i++) {
            float a = xv[i] + xrv[i];
            p1 = fmaf(at[i], a, p1);
            p2 = fmaf(at[i], fabsf(a), p2);
        }
        float p = fmaf(0.6f, p1, 0.4f * p2);
        p += __shfl_xor(p, 1, 64);
        p += __shfl_xor(p, 2, 64);
        p += __shfl_xor(p, 4, 64);
        p += __shfl_xor(p, 8, 64);
        if (__any(p > m + 20.f)) {
            float nm = fmaxf(m, p);
            float r  = __expf(m - nm);
            float w  = __expf(p - nm);
            s = fmaf(s, r, w);
#pragma unroll
            for (int i = 0; i < F; i++) acc[i] = fmaf(acc[i], r, w * xv[i]);
            m = nm;
        } else {
            float w = __expf(p - m);
            s += w;
#pragma unroll
            for (int i = 0; i < F; i++) acc[i] = fmaf(w, xv[i], acc[i]);
        }
    }

    float inv = 1.f / s;
#pragma unroll
    for (int i = 0; i < F; i++) acc[i] *= inv;
#pragma unroll
    for (int i = 0; i < F; i++) {
        acc[i] += __shfl_xor(acc[i], 16, 64);
        acc[i] += __shfl_xor(acc[i], 32, 64);
    }
    if (lane < 16) {
        if (OUT == 0) {
            unsigned short h[F], lo[F];
#pragma unroll
            for (int i = 0; i < F; i++) {
                float v = fmaf(acc[i], 0.25f, bias[lane * F + i]);
                v = fmaxf(v, 0.f);
                h[i] = f2bf(v);
                lo[i] = f2bf(v - bf2f(h[i]));
            }
            size_t base = (size_t)wv * (16 * F) + lane * F;
#pragma unroll
            for (int i = 0; i < F / 2; i++) {
                ((unsigned*)(Yhi + base))[i] = (unsigned)h[2 * i] | ((unsigned)h[2 * i + 1] << 16);
                ((unsigned*)(Ylo + base))[i] = (unsigned)lo[2 * i] | ((unsigned)lo[2 * i + 1] << 16);
            }
        } else {
            float* op = out + (size_t)wv * (16 * F) + lane * F;
#pragma unroll
            for (int i = 0; i < F; i++)
                op[i] = fmaf(acc[i], 0.25f, bias[lane * F + i]);
        }
    }
}

// ---------------------------------------------------------------------------

static inline size_t align256(size_t x) { return (x + 255) & ~(size_t)255; }

extern "C" void kernel_launch(void* const* d_in, const int* in_sizes, int n_in,
                              void* d_out, int out_size, void* d_ws, size_t ws_size,
                              hipStream_t stream) {
    const float* x  = (const float*)d_in[0];
    const int*   ei = (const int*)d_in[1];
    const int N  = in_sizes[0] / 9;
    const int E  = in_sizes[1] / 2;
    const int EP = E + N;
    const int* src = ei;
    const int* dst = ei + E;

    const float *Wl[3], *bl[3], *Wr[3], *br[3], *att[3], *bb[3];
    for (int i = 0; i < 3; i++) {
        Wl[i]  = (const float*)d_in[2 + 6 * i];
        bl[i]  = (const float*)d_in[3 + 6 * i];
        Wr[i]  = (const float*)d_in[4 + 6 * i];
        br[i]  = (const float*)d_in[5 + 6 * i];
        att[i] = (const float*)d_in[6 + 6 * i];
        bb[i]  = (const float*)d_in[7 + 6 * i];
    }

    // workspace layout (~131 MB)
    char* w = (char*)d_ws;
    unsigned short* xl  = (unsigned short*)w; w += align256((size_t)N * 512 * 2);
    unsigned short* xr  = (unsigned short*)w; w += align256((size_t)N * 512 * 2);
    unsigned short* A1h = (unsigned short*)w; w += align256((size_t)N * 64 * 2);
    unsigned short* A1l = (unsigned short*)w; w += align256((size_t)N * 64 * 2);
    unsigned short* A2h = (unsigned short*)w; w += align256((size_t)N * 64 * 2);
    unsigned short* A2l = (unsigned short*)w; w += align256((size_t)N * 64 * 2);
    int* offs   = (int*)w;  w += align256((size_t)(N + 1) * 4);
    int* cnt    = (int*)w;  w += align256((size_t)(2 * N) * 4);   // cnt + cnt2
    int* csrc   = (int*)w;  w += align256((size_t)EP * 4);
    int* partial = (int*)w; w += 4096;
    unsigned short* Wp1h = (unsigned short*)w; w += align256((size_t)32 * 1024 * 2);
    unsigned short* Wp1l = (unsigned short*)w; w += align256((size_t)32 * 1024 * 2);
    unsigned short* Wp2h = (unsigned short*)w; w += align256((size_t)64 * 1024 * 2);
    unsigned short* Wp2l = (unsigned short*)w; w += align256((size_t)64 * 1024 * 2);
    int* cnt2 = cnt + N;

    // ---- CSR build over dst (6 dispatches) ----
    zero_int_k<<<(2 * N + 255) / 256, 256, 0, stream>>>(cnt, 2 * N);
    count_k<<<(EP + 255) / 256, 256, 0, stream>>>(dst, cnt, E, EP);
    int nb = (N + 1023) / 1024;
    scan1_k<<<nb, 1024, 0, stream>>>(cnt, offs, partial, N);
    scan2_k<<<1, 64, 0, stream>>>(partial, nb);
    scan3_k<<<nb, 1024, 0, stream>>>(offs, partial, N);
    fill2_k<<<(EP + 255) / 256, 256, 0, stream>>>(src, dst, offs, cnt2, csrc, E, EP);

    // ---- pack L1/L2 weights (one dispatch) ----
    split_w2_k<<<(96 * 1024) / 256, 256, 0, stream>>>(
        Wl[1], Wr[1], Wp1h, Wp1l, Wl[2], Wr[2], Wp2h, Wp2l);

    const int nodeBlocks = (N + 3) / 4;
    const int gemmBlocks = (N + 63) / 64;

    // ---- layer 0: fully fused (fp32 exact), writes A1 hi/lo split ----
    node_l0_k<<<nodeBlocks, 256, 0, stream>>>(
        x, Wl[0], bl[0], Wr[0], br[0], att[0], bb[0], offs, csrc, A1h, A1l, N);

    // ---- layer 1: MFMA gemm + node pass -> A2 hi/lo split ----
    mfma_gemm_k<4><<<gemmBlocks, 256, 0, stream>>>(
        A1h, A1l, Wp1h, Wp1l, bl[1], br[1], xl, xr, N, 256);
    node_fused_k<4, 0><<<nodeBlocks, 256, 0, stream>>>(
        xl, xr, att[1], bb[1], offs, csrc, A2h, A2l, nullptr, N);

    // ---- layer 2: MFMA gemm + node pass -> fp32 d_out ----
    mfma_gemm_k<8><<<gemmBlocks, 256, 0, stream>>>(
        A2h, A2l, Wp2h, Wp2l, bl[2], br[2], xl, xr, N, 512);
    node_fused_k<8, 1><<<nodeBlocks, 256, 0, stream>>>(
        xl, xr, att[2], bb[2], offs, csrc, nullptr, nullptr, (float*)d_out, N);
}

// Round 10
// 463.291 us; speedup vs baseline: 1.7410x; 1.0054x over previous
//
#include <hip/hip_runtime.h>
#include <hip/hip_bf16.h>

// ---------------------------------------------------------------------------
// MultiHopGATv2, fused formulation v8.
//   L0: gemm2_bf16_k<9> (streaming vector gemm, bf16 xl/xr)
//       + node_fused_k<4,OUT=0> -> writes A1 hi/lo bf16 split directly.
//   L1/L2: split-precision bf16 MFMA gemm (Xhi@Whi + Xlo@Whi + Xhi@Wlo),
//       node_fused_k writes hi/lo split (L1) or fp32 d_out (L2).
//   CSR: zero(2N) -> count -> 3-step scan -> fill2 (offs + atomic cnt2).
// (r9's node_l0_k was latency-bound at 155us — reverted to the r8 split.)
// ---------------------------------------------------------------------------

typedef __attribute__((ext_vector_type(8))) short bf16x8;
typedef __attribute__((ext_vector_type(4))) float f32x4;

__device__ __forceinline__ float bflo(unsigned w) { return __uint_as_float(w << 16); }
__device__ __forceinline__ float bfhi(unsigned w) { return __uint_as_float(w & 0xffff0000u); }
__device__ __forceinline__ unsigned short f2bf(float v) {
    unsigned u = __float_as_uint(v);
    u = (u + 0x7fff + ((u >> 16) & 1)) >> 16;   // round-to-nearest-even
    return (unsigned short)u;
}
__device__ __forceinline__ float bf2f(unsigned short h) {
    return __uint_as_float((unsigned)h << 16);
}

// ---------------- CSR build ----------------

__global__ void zero_int_k(int* p, int n) {
    int i = blockIdx.x * 256 + threadIdx.x;
    if (i < n) p[i] = 0;
}

__global__ void count_k(const int* __restrict__ dst, int* __restrict__ cnt,
                        int E, int EP) {
    int e = blockIdx.x * 256 + threadIdx.x;
    if (e >= EP) return;
    int d = (e < E) ? dst[e] : (e - E);
    atomicAdd(&cnt[d], 1);
}

__global__ void scan1_k(const int* __restrict__ cnt, int* __restrict__ offs,
                        int* __restrict__ partial, int N) {
    __shared__ int buf[2][1024];
    int g = blockIdx.x * 1024 + threadIdx.x;
    int v = (g < N) ? cnt[g] : 0;
    int pi = 0;
    buf[0][threadIdx.x] = v;
    __syncthreads();
    for (int s = 1; s < 1024; s <<= 1) {
        int t = buf[pi][threadIdx.x];
        if ((int)threadIdx.x >= s) t += buf[pi][threadIdx.x - s];
        buf[pi ^ 1][threadIdx.x] = t;
        pi ^= 1;
        __syncthreads();
    }
    int incl = buf[pi][threadIdx.x];
    if (g < N) offs[g + 1] = incl;
    if (threadIdx.x == 1023) partial[blockIdx.x] = incl;
}

__global__ void scan2_k(int* partial, int nb) {
    if (blockIdx.x == 0 && threadIdx.x == 0) {
        int run = 0;
        for (int i = 0; i < nb; i++) { int t = partial[i]; partial[i] = run; run += t; }
    }
}

__global__ void scan3_k(int* __restrict__ offs, const int* __restrict__ partial, int N) {
    int g = blockIdx.x * 1024 + threadIdx.x;
    if (g < N) offs[g + 1] += partial[blockIdx.x];
    if (g == 0) offs[0] = 0;
}

__global__ void fill2_k(const int* __restrict__ src, const int* __restrict__ dst,
                        const int* __restrict__ offs, int* __restrict__ cnt2,
                        int* __restrict__ csrc, int E, int EP) {
    int e = blockIdx.x * 256 + threadIdx.x;
    if (e >= EP) return;
    int sv, d;
    if (e < E) { sv = src[e]; d = dst[e]; }
    else       { sv = e - E;  d = sv; }
    int p = offs[d] + atomicAdd(&cnt2[d], 1);
    csrc[p] = sv;
}

// ---------------- L0 vector gemm (FIN=9) ----------------
template <int FIN>
__global__ void gemm2_bf16_k(const float* __restrict__ X,
                             const float* __restrict__ Wl, const float* __restrict__ bl,
                             const float* __restrict__ Wr, const float* __restrict__ br,
                             unsigned short* __restrict__ xl, unsigned short* __restrict__ xr,
                             int N, int HCT) {
    constexpr int RPT = 16;
    __shared__ float Xs[RPT][FIN];
    int tid  = threadIdx.x;
    int col  = blockIdx.y * 256 + tid;
    int row0 = blockIdx.x * RPT;
    for (int i = tid; i < RPT * FIN; i += 256) {
        int r = i / FIN, k = i % FIN;
        int gr = row0 + r;
        Xs[r][k] = (gr < N) ? X[(size_t)gr * FIN + k] : 0.f;
    }
    __syncthreads();
    float aL[RPT], aR[RPT];
    float b1 = bl[col], b2 = br[col];
#pragma unroll
    for (int r = 0; r < RPT; r++) { aL[r] = b1; aR[r] = b2; }
    for (int k = 0; k < FIN; k++) {
        float wl = Wl[(size_t)k * HCT + col];
        float wr = Wr[(size_t)k * HCT + col];
#pragma unroll
        for (int r = 0; r < RPT; r++) {
            float xv = Xs[r][k];
            aL[r] = fmaf(xv, wl, aL[r]);
            aR[r] = fmaf(xv, wr, aR[r]);
        }
    }
#pragma unroll
    for (int r = 0; r < RPT; r++) {
        int gr = row0 + r;
        if (gr < N) {
            xl[(size_t)gr * HCT + col] = f2bf(aL[r]);
            xr[(size_t)gr * HCT + col] = f2bf(aR[r]);
        }
    }
}

// ---------------- pack W (L1 and L2) into MFMA B-frag order, hi/lo ----------
__device__ __forceinline__ void pack_one(const float* Wl, const float* Wr,
                                         unsigned short* Wh, unsigned short* Wlo,
                                         int HCT, int t) {
    int j  = t & 7;
    int l  = (t >> 3) & 63;
    int ks = (t >> 9) & 1;
    int ct = t >> 10;
    int k  = ks * 32 + (l >> 4) * 8 + j;
    int cg = ct * 16 + (l & 15);
    float v = (cg < HCT) ? Wl[(size_t)k * HCT + cg] : Wr[(size_t)k * HCT + (cg - HCT)];
    unsigned short hi = f2bf(v);
    Wh[t]  = hi;
    Wlo[t] = f2bf(v - bf2f(hi));
}

__global__ void split_w2_k(const float* __restrict__ Wl1, const float* __restrict__ Wr1,
                           unsigned short* __restrict__ W1h, unsigned short* __restrict__ W1l,
                           const float* __restrict__ Wl2, const float* __restrict__ Wr2,
                           unsigned short* __restrict__ W2h, unsigned short* __restrict__ W2l) {
    int tid = blockIdx.x * 256 + threadIdx.x;
    if (tid < 32 * 1024) pack_one(Wl1, Wr1, W1h, W1l, 256, tid);
    else                 pack_one(Wl2, Wr2, W2h, W2l, 512, tid - 32 * 1024);
}

// ---------------- MFMA gemm: [N x 64] @ [64 x HCT] x2 -> bf16 ----------------
template <int CHUNKS>
__global__ void mfma_gemm_k(const unsigned short* __restrict__ Ahi,
                            const unsigned short* __restrict__ Alo,
                            const unsigned short* __restrict__ Wphi,
                            const unsigned short* __restrict__ Wplo,
                            const float* __restrict__ bl, const float* __restrict__ br,
                            unsigned short* __restrict__ xl, unsigned short* __restrict__ xr,
                            int N, int HCT) {
    __shared__ float lds[4][16][128];
    int tid = threadIdx.x;
    int w   = tid >> 6, l = tid & 63;
    int l15 = l & 15,  seg = l >> 4;
    int row  = blockIdx.x * 64 + w * 16 + l15;
    int arow = (row < N) ? row : (N - 1);

    bf16x8 a0h = *(const bf16x8*)(Ahi + (size_t)arow * 64 + seg * 8);
    bf16x8 a1h = *(const bf16x8*)(Ahi + (size_t)arow * 64 + 32 + seg * 8);
    bf16x8 a0l = *(const bf16x8*)(Alo + (size_t)arow * 64 + seg * 8);
    bf16x8 a1l = *(const bf16x8*)(Alo + (size_t)arow * 64 + 32 + seg * 8);

    for (int c = 0; c < CHUNKS; c++) {
        int mat   = (c * 128) / HCT;
        int mcol0 = (c * 128) % HCT;
        const float* bias = mat ? br : bl;
        unsigned short* out = mat ? xr : xl;
        f32x4 acc[8];
#pragma unroll
        for (int t = 0; t < 8; t++) {
            float bv = bias[mcol0 + t * 16 + l15];
            acc[t] = (f32x4){bv, bv, bv, bv};
        }
#pragma unroll
        for (int t = 0; t < 8; t++) {
            size_t ct = (size_t)(c * 8 + t);
            bf16x8 b0h = *(const bf16x8*)(Wphi + ((ct * 2    ) * 64 + l) * 8);
            bf16x8 b1h = *(const bf16x8*)(Wphi + ((ct * 2 + 1) * 64 + l) * 8);
            bf16x8 b0l = *(const bf16x8*)(Wplo + ((ct * 2    ) * 64 + l) * 8);
            bf16x8 b1l = *(const bf16x8*)(Wplo + ((ct * 2 + 1) * 64 + l) * 8);
            acc[t] = __builtin_amdgcn_mfma_f32_16x16x32_bf16(a0h, b0h, acc[t], 0, 0, 0);
            acc[t] = __builtin_amdgcn_mfma_f32_16x16x32_bf16(a1h, b1h, acc[t], 0, 0, 0);
            acc[t] = __builtin_amdgcn_mfma_f32_16x16x32_bf16(a0l, b0h, acc[t], 0, 0, 0);
            acc[t] = __builtin_amdgcn_mfma_f32_16x16x32_bf16(a1l, b1h, acc[t], 0, 0, 0);
            acc[t] = __builtin_amdgcn_mfma_f32_16x16x32_bf16(a0h, b0l, acc[t], 0, 0, 0);
            acc[t] = __builtin_amdgcn_mfma_f32_16x16x32_bf16(a1h, b1l, acc[t], 0, 0, 0);
        }
#pragma unroll
        for (int t = 0; t < 8; t++)
#pragma unroll
            for (int r = 0; r < 4; r++)
                lds[w][seg * 4 + r][t * 16 + l15] = acc[t][r];
#pragma unroll
        for (int r = 0; r < 16; r++) {
            int orow = blockIdx.x * 64 + w * 16 + r;
            if (orow < N) {
                float v0 = lds[w][r][2 * l];
                float v1 = lds[w][r][2 * l + 1];
                unsigned pack = (unsigned)f2bf(v0) | ((unsigned)f2bf(v1) << 16);
                *(unsigned*)(out + (size_t)orow * HCT + mcol0 + 2 * l) = pack;
            }
        }
    }
}

// ---------------- fused node pass ----------------
// OUT=0: write relu(res) as hi/lo bf16 split [N,16F]  (feeds next MFMA gemm)
// OUT=1: write res as fp32 [N,16F] (final output, no relu)
template <int F, int OUT>
__global__ void node_fused_k(const unsigned short* __restrict__ xl,
                             const unsigned short* __restrict__ xr,
                             const float* __restrict__ att, const float* __restrict__ bias,
                             const int* __restrict__ offs, const int* __restrict__ csrc,
                             unsigned short* __restrict__ Yhi, unsigned short* __restrict__ Ylo,
                             float* __restrict__ out, int N) {
    constexpr int HCT = 64 * F;
    constexpr int NW  = F / 2;
    int wv   = blockIdx.x * 4 + (threadIdx.x >> 6);
    int lane = threadIdx.x & 63;
    if (wv >= N) return;

    float xrv[F], at[F];
    {
        const unsigned* xp = (const unsigned*)(xr + (size_t)wv * HCT + lane * F);
#pragma unroll
        for (int i = 0; i < NW; i++) {
            unsigned w = xp[i];
            xrv[2 * i] = bflo(w); xrv[2 * i + 1] = bfhi(w);
        }
#pragma unroll
        for (int i = 0; i < F; i++) at[i] = att[lane * F + i];
    }

    int o0 = offs[wv], o1 = offs[wv + 1];
    float m = -1e30f, s = 0.f;
    float acc[F];
#pragma unroll
    for (int i = 0; i < F; i++) acc[i] = 0.f;

    for (int j = o0; j < o1; ++j) {
        int sn = csrc[j];
        const unsigned* xp = (const unsigned*)(xl + (size_t)sn * HCT + lane * F);
        float xv[F];
#pragma unroll
        for (int i = 0; i < NW; i++) {
            unsigned w = xp[i];
            xv[2 * i] = bflo(w); xv[2 * i + 1] = bfhi(w);
        }
        float p1 = 0.f, p2 = 0.f;
#pragma unroll
        for (int i = 0; i < F; i++) {
            float a = xv[i] + xrv[i];
            p1 = fmaf(at[i], a, p1);
            p2 = fmaf(at[i], fabsf(a), p2);
        }
        float p = fmaf(0.6f, p1, 0.4f * p2);
        p += __shfl_xor(p, 1, 64);
        p += __shfl_xor(p, 2, 64);
        p += __shfl_xor(p, 4, 64);
        p += __shfl_xor(p, 8, 64);
        if (__any(p > m + 20.f)) {
            float nm = fmaxf(m, p);
            float r  = __expf(m - nm);
            float w  = __expf(p - nm);
            s = fmaf(s, r, w);
#pragma unroll
            for (int i = 0; i < F; i++) acc[i] = fmaf(acc[i], r, w * xv[i]);
            m = nm;
        } else {
            float w = __expf(p - m);
            s += w;
#pragma unroll
            for (int i = 0; i < F; i++) acc[i] = fmaf(w, xv[i], acc[i]);
        }
    }

    float inv = 1.f / s;
#pragma unroll
    for (int i = 0; i < F; i++) acc[i] *= inv;
#pragma unroll
    for (int i = 0; i < F; i++) {
        acc[i] += __shfl_xor(acc[i], 16, 64);
        acc[i] += __shfl_xor(acc[i], 32, 64);
    }
    if (lane < 16) {
        if (OUT == 0) {
            unsigned short h[F], lo[F];
#pragma unroll
            for (int i = 0; i < F; i++) {
                float v = fmaf(acc[i], 0.25f, bias[lane * F + i]);
                v = fmaxf(v, 0.f);
                h[i] = f2bf(v);
                lo[i] = f2bf(v - bf2f(h[i]));
            }
            size_t base = (size_t)wv * (16 * F) + lane * F;
#pragma unroll
            for (int i = 0; i < F / 2; i++) {
                ((unsigned*)(Yhi + base))[i] = (unsigned)h[2 * i] | ((unsigned)h[2 * i + 1] << 16);
                ((unsigned*)(Ylo + base))[i] = (unsigned)lo[2 * i] | ((unsigned)lo[2 * i + 1] << 16);
            }
        } else {
            float* op = out + (size_t)wv * (16 * F) + lane * F;
#pragma unroll
            for (int i = 0; i < F; i++)
                op[i] = fmaf(acc[i], 0.25f, bias[lane * F + i]);
        }
    }
}

// ---------------------------------------------------------------------------

static inline size_t align256(size_t x) { return (x + 255) & ~(size_t)255; }

extern "C" void kernel_launch(void* const* d_in, const int* in_sizes, int n_in,
                              void* d_out, int out_size, void* d_ws, size_t ws_size,
                              hipStream_t stream) {
    const float* x  = (const float*)d_in[0];
    const int*   ei = (const int*)d_in[1];
    const int N  = in_sizes[0] / 9;
    const int E  = in_sizes[1] / 2;
    const int EP = E + N;
    const int* src = ei;
    const int* dst = ei + E;

    const float *Wl[3], *bl[3], *Wr[3], *br[3], *att[3], *bb[3];
    for (int i = 0; i < 3; i++) {
        Wl[i]  = (const float*)d_in[2 + 6 * i];
        bl[i]  = (const float*)d_in[3 + 6 * i];
        Wr[i]  = (const float*)d_in[4 + 6 * i];
        br[i]  = (const float*)d_in[5 + 6 * i];
        att[i] = (const float*)d_in[6 + 6 * i];
        bb[i]  = (const float*)d_in[7 + 6 * i];
    }

    // workspace layout (~131 MB)
    char* w = (char*)d_ws;
    unsigned short* xl  = (unsigned short*)w; w += align256((size_t)N * 512 * 2);
    unsigned short* xr  = (unsigned short*)w; w += align256((size_t)N * 512 * 2);
    unsigned short* A1h = (unsigned short*)w; w += align256((size_t)N * 64 * 2);
    unsigned short* A1l = (unsigned short*)w; w += align256((size_t)N * 64 * 2);
    unsigned short* A2h = (unsigned short*)w; w += align256((size_t)N * 64 * 2);
    unsigned short* A2l = (unsigned short*)w; w += align256((size_t)N * 64 * 2);
    int* offs   = (int*)w;  w += align256((size_t)(N + 1) * 4);
    int* cnt    = (int*)w;  w += align256((size_t)(2 * N) * 4);   // cnt + cnt2
    int* csrc   = (int*)w;  w += align256((size_t)EP * 4);
    int* partial = (int*)w; w += 4096;
    unsigned short* Wp1h = (unsigned short*)w; w += align256((size_t)32 * 1024 * 2);
    unsigned short* Wp1l = (unsigned short*)w; w += align256((size_t)32 * 1024 * 2);
    unsigned short* Wp2h = (unsigned short*)w; w += align256((size_t)64 * 1024 * 2);
    unsigned short* Wp2l = (unsigned short*)w; w += align256((size_t)64 * 1024 * 2);
    int* cnt2 = cnt + N;

    // ---- CSR build over dst (6 dispatches) ----
    zero_int_k<<<(2 * N + 255) / 256, 256, 0, stream>>>(cnt, 2 * N);
    count_k<<<(EP + 255) / 256, 256, 0, stream>>>(dst, cnt, E, EP);
    int nb = (N + 1023) / 1024;
    scan1_k<<<nb, 1024, 0, stream>>>(cnt, offs, partial, N);
    scan2_k<<<1, 64, 0, stream>>>(partial, nb);
    scan3_k<<<nb, 1024, 0, stream>>>(offs, partial, N);
    fill2_k<<<(EP + 255) / 256, 256, 0, stream>>>(src, dst, offs, cnt2, csrc, E, EP);

    // ---- pack L1/L2 weights (one dispatch) ----
    split_w2_k<<<(96 * 1024) / 256, 256, 0, stream>>>(
        Wl[1], Wr[1], Wp1h, Wp1l, Wl[2], Wr[2], Wp2h, Wp2l);

    const int nodeBlocks = (N + 3) / 4;
    const int gemmBlocks = (N + 63) / 64;

    // ---- layer 0: vector gemm + node pass -> A1 hi/lo split ----
    dim3 g1((N + 15) / 16, 1);
    gemm2_bf16_k<9><<<g1, 256, 0, stream>>>(
        x, Wl[0], bl[0], Wr[0], br[0], xl, xr, N, 256);
    node_fused_k<4, 0><<<nodeBlocks, 256, 0, stream>>>(
        xl, xr, att[0], bb[0], offs, csrc, A1h, A1l, nullptr, N);

    // ---- layer 1: MFMA gemm + node pass -> A2 hi/lo split ----
    mfma_gemm_k<4><<<gemmBlocks, 256, 0, stream>>>(
        A1h, A1l, Wp1h, Wp1l, bl[1], br[1], xl, xr, N, 256);
    node_fused_k<4, 0><<<nodeBlocks, 256, 0, stream>>>(
        xl, xr, att[1], bb[1], offs, csrc, A2h, A2l, nullptr, N);

    // ---- layer 2: MFMA gemm + node pass -> fp32 d_out ----
    mfma_gemm_k<8><<<gemmBlocks, 256, 0, stream>>>(
        A2h, A2l, Wp2h, Wp2l, bl[2], br[2], xl, xr, N, 512);
    node_fused_k<8, 1><<<nodeBlocks, 256, 0, stream>>>(
        xl, xr, att[2], bb[2], offs, csrc, nullptr, nullptr, (float*)d_out, N);
}

// Round 11
// 455.443 us; speedup vs baseline: 1.7710x; 1.0172x over previous
//
#include <hip/hip_runtime.h>
#include <hip/hip_bf16.h>

// ---------------------------------------------------------------------------
// MultiHopGATv2, fused formulation v9.
//   xl/xr stored fp16 (better mantissa than bf16 + enables packed math).
//   node_fused: per-edge logit via v_pk_add_f16 + v_dot2_f32_f16 (1 op = 2
//   fma), lrelu fold via packed abs mask; acc accumulates w*a (a=xv+xr) in
//   packed f32; epilogue: out = acc/s - xr per head, then head-sum shuffles.
//   L1/L2 GEMMs: split-precision bf16 MFMA (unchanged A-path).
//   CSR: zero -> count -> scan1 -> scan23(merged) -> fill2.  12 dispatches.
// ---------------------------------------------------------------------------

typedef __attribute__((ext_vector_type(8))) short bf16x8;
typedef __attribute__((ext_vector_type(4))) float f32x4;
typedef _Float16 f16;
typedef __attribute__((ext_vector_type(2))) _Float16 h2;
typedef __attribute__((ext_vector_type(2))) float f2;

__device__ __forceinline__ unsigned short f2bf(float v) {
    unsigned u = __float_as_uint(v);
    u = (u + 0x7fff + ((u >> 16) & 1)) >> 16;   // round-to-nearest-even
    return (unsigned short)u;
}
__device__ __forceinline__ float bf2f(unsigned short h) {
    return __uint_as_float((unsigned)h << 16);
}

// ---------------- CSR build ----------------

__global__ void zero_int_k(int* p, int n) {
    int i = blockIdx.x * 256 + threadIdx.x;
    if (i < n) p[i] = 0;
}

__global__ void count_k(const int* __restrict__ dst, int* __restrict__ cnt,
                        int E, int EP) {
    int e = blockIdx.x * 256 + threadIdx.x;
    if (e >= EP) return;
    int d = (e < E) ? dst[e] : (e - E);
    atomicAdd(&cnt[d], 1);
}

__global__ void scan1_k(const int* __restrict__ cnt, int* __restrict__ offs,
                        int* __restrict__ partial, int N) {
    __shared__ int buf[2][1024];
    int g = blockIdx.x * 1024 + threadIdx.x;
    int v = (g < N) ? cnt[g] : 0;
    int pi = 0;
    buf[0][threadIdx.x] = v;
    __syncthreads();
    for (int s = 1; s < 1024; s <<= 1) {
        int t = buf[pi][threadIdx.x];
        if ((int)threadIdx.x >= s) t += buf[pi][threadIdx.x - s];
        buf[pi ^ 1][threadIdx.x] = t;
        pi ^= 1;
        __syncthreads();
    }
    int incl = buf[pi][threadIdx.x];
    if (g < N) offs[g + 1] = incl;
    if (threadIdx.x == 1023) partial[blockIdx.x] = incl;
}

// merged scan2+scan3: each block wave-reduces partial[0..blockIdx) then adds.
__global__ void scan23_k(int* __restrict__ offs, const int* __restrict__ partial, int N) {
    __shared__ float dummy;
    __shared__ int preS;
    int b = blockIdx.x;
    if (threadIdx.x < 64) {
        int t = threadIdx.x;
        int v = (t < b) ? partial[t] : 0;
#pragma unroll
        for (int o = 32; o > 0; o >>= 1) v += __shfl_xor(v, o, 64);
        if (t == 0) preS = v;
    }
    __syncthreads();
    int pre = preS;
    int g = b * 1024 + threadIdx.x;
    if (g < N) offs[g + 1] += pre;
    if (g == 0) offs[0] = 0;
    (void)dummy;
}

__global__ void fill2_k(const int* __restrict__ src, const int* __restrict__ dst,
                        const int* __restrict__ offs, int* __restrict__ cnt2,
                        int* __restrict__ csrc, int E, int EP) {
    int e = blockIdx.x * 256 + threadIdx.x;
    if (e >= EP) return;
    int sv, d;
    if (e < E) { sv = src[e]; d = dst[e]; }
    else       { sv = e - E;  d = sv; }
    int p = offs[d] + atomicAdd(&cnt2[d], 1);
    csrc[p] = sv;
}

// ---------------- L0 vector gemm (FIN=9), fp16 out ----------------
template <int FIN>
__global__ void gemm2_f16_k(const float* __restrict__ X,
                            const float* __restrict__ Wl, const float* __restrict__ bl,
                            const float* __restrict__ Wr, const float* __restrict__ br,
                            unsigned short* __restrict__ xl, unsigned short* __restrict__ xr,
                            int N, int HCT) {
    constexpr int RPT = 16;
    __shared__ float Xs[RPT][FIN];
    int tid  = threadIdx.x;
    int col  = blockIdx.y * 256 + tid;
    int row0 = blockIdx.x * RPT;
    for (int i = tid; i < RPT * FIN; i += 256) {
        int r = i / FIN, k = i % FIN;
        int gr = row0 + r;
        Xs[r][k] = (gr < N) ? X[(size_t)gr * FIN + k] : 0.f;
    }
    __syncthreads();
    float aL[RPT], aR[RPT];
    float b1 = bl[col], b2 = br[col];
#pragma unroll
    for (int r = 0; r < RPT; r++) { aL[r] = b1; aR[r] = b2; }
    for (int k = 0; k < FIN; k++) {
        float wl = Wl[(size_t)k * HCT + col];
        float wr = Wr[(size_t)k * HCT + col];
#pragma unroll
        for (int r = 0; r < RPT; r++) {
            float xv = Xs[r][k];
            aL[r] = fmaf(xv, wl, aL[r]);
            aR[r] = fmaf(xv, wr, aR[r]);
        }
    }
#pragma unroll
    for (int r = 0; r < RPT; r++) {
        int gr = row0 + r;
        if (gr < N) {
            xl[(size_t)gr * HCT + col] = __builtin_bit_cast(unsigned short, (f16)aL[r]);
            xr[(size_t)gr * HCT + col] = __builtin_bit_cast(unsigned short, (f16)aR[r]);
        }
    }
}

// ---------------- pack W (L1 and L2) into MFMA B-frag order, hi/lo ----------
__device__ __forceinline__ void pack_one(const float* Wl, const float* Wr,
                                         unsigned short* Wh, unsigned short* Wlo,
                                         int HCT, int t) {
    int j  = t & 7;
    int l  = (t >> 3) & 63;
    int ks = (t >> 9) & 1;
    int ct = t >> 10;
    int k  = ks * 32 + (l >> 4) * 8 + j;
    int cg = ct * 16 + (l & 15);
    float v = (cg < HCT) ? Wl[(size_t)k * HCT + cg] : Wr[(size_t)k * HCT + (cg - HCT)];
    unsigned short hi = f2bf(v);
    Wh[t]  = hi;
    Wlo[t] = f2bf(v - bf2f(hi));
}

__global__ void split_w2_k(const float* __restrict__ Wl1, const float* __restrict__ Wr1,
                           unsigned short* __restrict__ W1h, unsigned short* __restrict__ W1l,
                           const float* __restrict__ Wl2, const float* __restrict__ Wr2,
                           unsigned short* __restrict__ W2h, unsigned short* __restrict__ W2l) {
    int tid = blockIdx.x * 256 + threadIdx.x;
    if (tid < 32 * 1024) pack_one(Wl1, Wr1, W1h, W1l, 256, tid);
    else                 pack_one(Wl2, Wr2, W2h, W2l, 512, tid - 32 * 1024);
}

// ---------------- MFMA gemm: [N x 64] @ [64 x HCT] x2 -> fp16 ----------------
template <int CHUNKS>
__global__ void mfma_gemm_k(const unsigned short* __restrict__ Ahi,
                            const unsigned short* __restrict__ Alo,
                            const unsigned short* __restrict__ Wphi,
                            const unsigned short* __restrict__ Wplo,
                            const float* __restrict__ bl, const float* __restrict__ br,
                            unsigned short* __restrict__ xl, unsigned short* __restrict__ xr,
                            int N, int HCT) {
    __shared__ float lds[4][16][128];
    int tid = threadIdx.x;
    int w   = tid >> 6, l = tid & 63;
    int l15 = l & 15,  seg = l >> 4;
    int row  = blockIdx.x * 64 + w * 16 + l15;
    int arow = (row < N) ? row : (N - 1);

    bf16x8 a0h = *(const bf16x8*)(Ahi + (size_t)arow * 64 + seg * 8);
    bf16x8 a1h = *(const bf16x8*)(Ahi + (size_t)arow * 64 + 32 + seg * 8);
    bf16x8 a0l = *(const bf16x8*)(Alo + (size_t)arow * 64 + seg * 8);
    bf16x8 a1l = *(const bf16x8*)(Alo + (size_t)arow * 64 + 32 + seg * 8);

    for (int c = 0; c < CHUNKS; c++) {
        int mat   = (c * 128) / HCT;
        int mcol0 = (c * 128) % HCT;
        const float* bias = mat ? br : bl;
        unsigned short* out = mat ? xr : xl;
        f32x4 acc[8];
#pragma unroll
        for (int t = 0; t < 8; t++) {
            float bv = bias[mcol0 + t * 16 + l15];
            acc[t] = (f32x4){bv, bv, bv, bv};
        }
#pragma unroll
        for (int t = 0; t < 8; t++) {
            size_t ct = (size_t)(c * 8 + t);
            bf16x8 b0h = *(const bf16x8*)(Wphi + ((ct * 2    ) * 64 + l) * 8);
            bf16x8 b1h = *(const bf16x8*)(Wphi + ((ct * 2 + 1) * 64 + l) * 8);
            bf16x8 b0l = *(const bf16x8*)(Wplo + ((ct * 2    ) * 64 + l) * 8);
            bf16x8 b1l = *(const bf16x8*)(Wplo + ((ct * 2 + 1) * 64 + l) * 8);
            acc[t] = __builtin_amdgcn_mfma_f32_16x16x32_bf16(a0h, b0h, acc[t], 0, 0, 0);
            acc[t] = __builtin_amdgcn_mfma_f32_16x16x32_bf16(a1h, b1h, acc[t], 0, 0, 0);
            acc[t] = __builtin_amdgcn_mfma_f32_16x16x32_bf16(a0l, b0h, acc[t], 0, 0, 0);
            acc[t] = __builtin_amdgcn_mfma_f32_16x16x32_bf16(a1l, b1h, acc[t], 0, 0, 0);
            acc[t] = __builtin_amdgcn_mfma_f32_16x16x32_bf16(a0h, b0l, acc[t], 0, 0, 0);
            acc[t] = __builtin_amdgcn_mfma_f32_16x16x32_bf16(a1h, b1l, acc[t], 0, 0, 0);
        }
#pragma unroll
        for (int t = 0; t < 8; t++)
#pragma unroll
            for (int r = 0; r < 4; r++)
                lds[w][seg * 4 + r][t * 16 + l15] = acc[t][r];
#pragma unroll
        for (int r = 0; r < 16; r++) {
            int orow = blockIdx.x * 64 + w * 16 + r;
            if (orow < N) {
                float v0 = lds[w][r][2 * l];
                float v1 = lds[w][r][2 * l + 1];
                h2 hv = { (f16)v0, (f16)v1 };
                *(unsigned*)(out + (size_t)orow * HCT + mcol0 + 2 * l) =
                    __builtin_bit_cast(unsigned, hv);
            }
        }
    }
}

// ---------------- fused node pass (fp16 inputs, dot2 logits) ----------------
// OUT=0: write relu(res) as hi/lo bf16 split [N,16F]  (feeds next MFMA gemm)
// OUT=1: write res as fp32 [N,16F] (final output, no relu)
// acc accumulates w*a where a = xv+xr; out = acc/s - xr (per head).
template <int F, int OUT>
__global__ void node_fused_k(const unsigned short* __restrict__ xl,
                             const unsigned short* __restrict__ xr,
                             const float* __restrict__ att, const float* __restrict__ bias,
                             const int* __restrict__ offs, const int* __restrict__ csrc,
                             unsigned short* __restrict__ Yhi, unsigned short* __restrict__ Ylo,
                             float* __restrict__ out, int N) {
    constexpr int HCT = 64 * F;
    constexpr int NW  = F / 2;
    int wv   = blockIdx.x * 4 + (threadIdx.x >> 6);
    int lane = threadIdx.x & 63;
    if (wv >= N) return;

    h2 xrh[NW], ath[NW];
    f2 xrf[NW];
    {
        const unsigned* xp = (const unsigned*)(xr + (size_t)wv * HCT + lane * F);
#pragma unroll
        for (int i = 0; i < NW; i++) {
            xrh[i] = __builtin_bit_cast(h2, xp[i]);
            xrf[i] = __builtin_convertvector(xrh[i], f2);
            ath[i] = h2{ (f16)att[lane * F + 2 * i], (f16)att[lane * F + 2 * i + 1] };
        }
    }

    int o0 = offs[wv], o1 = offs[wv + 1];
    float m = -1e30f, s = 0.f;
    f2 acc[NW];
#pragma unroll
    for (int i = 0; i < NW; i++) acc[i] = f2{0.f, 0.f};

    for (int j = o0; j < o1; ++j) {
        int sn = csrc[j];
        const unsigned* xp = (const unsigned*)(xl + (size_t)sn * HCT + lane * F);
        h2 a[NW];
        float p1 = 0.f, p2 = 0.f;
#pragma unroll
        for (int i = 0; i < NW; i++) {
            h2 xv = __builtin_bit_cast(h2, xp[i]);
            a[i] = xv + xrh[i];                              // v_pk_add_f16
            unsigned au = __builtin_bit_cast(unsigned, a[i]) & 0x7FFF7FFFu;
            h2 aa = __builtin_bit_cast(h2, au);              // |a| packed
            p1 = __builtin_amdgcn_fdot2(ath[i], a[i], p1, false);
            p2 = __builtin_amdgcn_fdot2(ath[i], aa,   p2, false);
        }
        float p = fmaf(0.6f, p1, 0.4f * p2);                 // lrelu fold
        p += __shfl_xor(p, 1, 64);
        p += __shfl_xor(p, 2, 64);
        p += __shfl_xor(p, 4, 64);
        p += __shfl_xor(p, 8, 64);
        f2 af[NW];
#pragma unroll
        for (int i = 0; i < NW; i++) af[i] = __builtin_convertvector(a[i], f2);
        if (__any(p > m + 20.f)) {                           // rare: raise max
            float nm = fmaxf(m, p);
            float r  = __expf(m - nm);
            float w  = __expf(p - nm);
            s = fmaf(s, r, w);
            f2 r2 = {r, r}, w2 = {w, w};
#pragma unroll
            for (int i = 0; i < NW; i++)
                acc[i] = __builtin_elementwise_fma(acc[i], r2, af[i] * w2);
            m = nm;
        } else {                                              // common path
            float w = __expf(p - m);
            s += w;
            f2 w2 = {w, w};
#pragma unroll
            for (int i = 0; i < NW; i++)
                acc[i] = __builtin_elementwise_fma(af[i], w2, acc[i]);   // v_pk_fma_f32
        }
    }

    float inv = 1.f / s;
    f2 inv2 = {inv, inv};
    float val[F];
#pragma unroll
    for (int i = 0; i < NW; i++) {
        f2 v = __builtin_elementwise_fma(acc[i], inv2, -xrf[i]);  // acc/s - xr
        val[2 * i] = v.x; val[2 * i + 1] = v.y;
    }
#pragma unroll
    for (int i = 0; i < F; i++) {                 // sum the 4 heads
        val[i] += __shfl_xor(val[i], 16, 64);
        val[i] += __shfl_xor(val[i], 32, 64);
    }
    if (lane < 16) {
        if (OUT == 0) {
            unsigned short h[F], lo[F];
#pragma unroll
            for (int i = 0; i < F; i++) {
                float v = fmaf(val[i], 0.25f, bias[lane * F + i]);
                v = fmaxf(v, 0.f);
                h[i] = f2bf(v);
                lo[i] = f2bf(v - bf2f(h[i]));
            }
            size_t base = (size_t)wv * (16 * F) + lane * F;
#pragma unroll
            for (int i = 0; i < F / 2; i++) {
                ((unsigned*)(Yhi + base))[i] = (unsigned)h[2 * i] | ((unsigned)h[2 * i + 1] << 16);
                ((unsigned*)(Ylo + base))[i] = (unsigned)lo[2 * i] | ((unsigned)lo[2 * i + 1] << 16);
            }
        } else {
            float* op = out + (size_t)wv * (16 * F) + lane * F;
#pragma unroll
            for (int i = 0; i < F; i++)
                op[i] = fmaf(val[i], 0.25f, bias[lane * F + i]);
        }
    }
}

// ---------------------------------------------------------------------------

static inline size_t align256(size_t x) { return (x + 255) & ~(size_t)255; }

extern "C" void kernel_launch(void* const* d_in, const int* in_sizes, int n_in,
                              void* d_out, int out_size, void* d_ws, size_t ws_size,
                              hipStream_t stream) {
    const float* x  = (const float*)d_in[0];
    const int*   ei = (const int*)d_in[1];
    const int N  = in_sizes[0] / 9;
    const int E  = in_sizes[1] / 2;
    const int EP = E + N;
    const int* src = ei;
    const int* dst = ei + E;

    const float *Wl[3], *bl[3], *Wr[3], *br[3], *att[3], *bb[3];
    for (int i = 0; i < 3; i++) {
        Wl[i]  = (const float*)d_in[2 + 6 * i];
        bl[i]  = (const float*)d_in[3 + 6 * i];
        Wr[i]  = (const float*)d_in[4 + 6 * i];
        br[i]  = (const float*)d_in[5 + 6 * i];
        att[i] = (const float*)d_in[6 + 6 * i];
        bb[i]  = (const float*)d_in[7 + 6 * i];
    }

    // workspace layout (~131 MB)
    char* w = (char*)d_ws;
    unsigned short* xl  = (unsigned short*)w; w += align256((size_t)N * 512 * 2);
    unsigned short* xr  = (unsigned short*)w; w += align256((size_t)N * 512 * 2);
    unsigned short* A1h = (unsigned short*)w; w += align256((size_t)N * 64 * 2);
    unsigned short* A1l = (unsigned short*)w; w += align256((size_t)N * 64 * 2);
    unsigned short* A2h = (unsigned short*)w; w += align256((size_t)N * 64 * 2);
    unsigned short* A2l = (unsigned short*)w; w += align256((size_t)N * 64 * 2);
    int* offs   = (int*)w;  w += align256((size_t)(N + 1) * 4);
    int* cnt    = (int*)w;  w += align256((size_t)(2 * N) * 4);   // cnt + cnt2
    int* csrc   = (int*)w;  w += align256((size_t)EP * 4);
    int* partial = (int*)w; w += 4096;
    unsigned short* Wp1h = (unsigned short*)w; w += align256((size_t)32 * 1024 * 2);
    unsigned short* Wp1l = (unsigned short*)w; w += align256((size_t)32 * 1024 * 2);
    unsigned short* Wp2h = (unsigned short*)w; w += align256((size_t)64 * 1024 * 2);
    unsigned short* Wp2l = (unsigned short*)w; w += align256((size_t)64 * 1024 * 2);
    int* cnt2 = cnt + N;

    // ---- CSR build over dst (5 dispatches) ----
    zero_int_k<<<(2 * N + 255) / 256, 256, 0, stream>>>(cnt, 2 * N);
    count_k<<<(EP + 255) / 256, 256, 0, stream>>>(dst, cnt, E, EP);
    int nb = (N + 1023) / 1024;
    scan1_k<<<nb, 1024, 0, stream>>>(cnt, offs, partial, N);
    scan23_k<<<nb, 1024, 0, stream>>>(offs, partial, N);
    fill2_k<<<(EP + 255) / 256, 256, 0, stream>>>(src, dst, offs, cnt2, csrc, E, EP);

    // ---- pack L1/L2 weights (one dispatch) ----
    split_w2_k<<<(96 * 1024) / 256, 256, 0, stream>>>(
        Wl[1], Wr[1], Wp1h, Wp1l, Wl[2], Wr[2], Wp2h, Wp2l);

    const int nodeBlocks = (N + 3) / 4;
    const int gemmBlocks = (N + 63) / 64;

    // ---- layer 0: vector gemm + node pass -> A1 hi/lo split ----
    dim3 g1((N + 15) / 16, 1);
    gemm2_f16_k<9><<<g1, 256, 0, stream>>>(
        x, Wl[0], bl[0], Wr[0], br[0], xl, xr, N, 256);
    node_fused_k<4, 0><<<nodeBlocks, 256, 0, stream>>>(
        xl, xr, att[0], bb[0], offs, csrc, A1h, A1l, nullptr, N);

    // ---- layer 1: MFMA gemm + node pass -> A2 hi/lo split ----
    mfma_gemm_k<4><<<gemmBlocks, 256, 0, stream>>>(
        A1h, A1l, Wp1h, Wp1l, bl[1], br[1], xl, xr, N, 256);
    node_fused_k<4, 0><<<nodeBlocks, 256, 0, stream>>>(
        xl, xr, att[1], bb[1], offs, csrc, A2h, A2l, nullptr, N);

    // ---- layer 2: MFMA gemm + node pass -> fp32 d_out ----
    mfma_gemm_k<8><<<gemmBlocks, 256, 0, stream>>>(
        A2h, A2l, Wp2h, Wp2l, bl[2], br[2], xl, xr, N, 512);
    node_fused_k<8, 1><<<nodeBlocks, 256, 0, stream>>>(
        xl, xr, att[2], bb[2], offs, csrc, nullptr, nullptr, (float*)d_out, N);
}

// Round 12
// 395.055 us; speedup vs baseline: 2.0417x; 1.1529x over previous
//
#include <hip/hip_runtime.h>
#include <hip/hip_bf16.h>

// ---------------------------------------------------------------------------
// MultiHopGATv2, fused formulation v10.
//   xl/xr stored fp16; node_fused processes TWO edges per iteration (2
//   independent row gathers in flight per wave -> hides L2/L3 latency,
//   the measured bottleneck: r11 showed time ~ edge count, not bytes).
//   Deferred-max softmax: pair fast path = 2 exp + packed fmas; rare
//   new-max path exact-sequential. Odd tail handled first (inits m).
//   L1/L2 GEMMs: split-precision bf16 MFMA (unchanged).
//   CSR: zero -> count -> scan1 -> scan23 -> fill2.  12 dispatches.
// ---------------------------------------------------------------------------

typedef __attribute__((ext_vector_type(8))) short bf16x8;
typedef __attribute__((ext_vector_type(4))) float f32x4;
typedef _Float16 f16;
typedef __attribute__((ext_vector_type(2))) _Float16 h2;
typedef __attribute__((ext_vector_type(2))) float f2;

__device__ __forceinline__ unsigned short f2bf(float v) {
    unsigned u = __float_as_uint(v);
    u = (u + 0x7fff + ((u >> 16) & 1)) >> 16;   // round-to-nearest-even
    return (unsigned short)u;
}
__device__ __forceinline__ float bf2f(unsigned short h) {
    return __uint_as_float((unsigned)h << 16);
}

// ---------------- CSR build ----------------

__global__ void zero_int_k(int* p, int n) {
    int i = blockIdx.x * 256 + threadIdx.x;
    if (i < n) p[i] = 0;
}

__global__ void count_k(const int* __restrict__ dst, int* __restrict__ cnt,
                        int E, int EP) {
    int e = blockIdx.x * 256 + threadIdx.x;
    if (e >= EP) return;
    int d = (e < E) ? dst[e] : (e - E);
    atomicAdd(&cnt[d], 1);
}

__global__ void scan1_k(const int* __restrict__ cnt, int* __restrict__ offs,
                        int* __restrict__ partial, int N) {
    __shared__ int buf[2][1024];
    int g = blockIdx.x * 1024 + threadIdx.x;
    int v = (g < N) ? cnt[g] : 0;
    int pi = 0;
    buf[0][threadIdx.x] = v;
    __syncthreads();
    for (int s = 1; s < 1024; s <<= 1) {
        int t = buf[pi][threadIdx.x];
        if ((int)threadIdx.x >= s) t += buf[pi][threadIdx.x - s];
        buf[pi ^ 1][threadIdx.x] = t;
        pi ^= 1;
        __syncthreads();
    }
    int incl = buf[pi][threadIdx.x];
    if (g < N) offs[g + 1] = incl;
    if (threadIdx.x == 1023) partial[blockIdx.x] = incl;
}

// merged scan2+scan3
__global__ void scan23_k(int* __restrict__ offs, const int* __restrict__ partial, int N) {
    __shared__ int preS;
    int b = blockIdx.x;
    if (threadIdx.x < 64) {
        int t = threadIdx.x;
        int v = (t < b) ? partial[t] : 0;
#pragma unroll
        for (int o = 32; o > 0; o >>= 1) v += __shfl_xor(v, o, 64);
        if (t == 0) preS = v;
    }
    __syncthreads();
    int pre = preS;
    int g = b * 1024 + threadIdx.x;
    if (g < N) offs[g + 1] += pre;
    if (g == 0) offs[0] = 0;
}

__global__ void fill2_k(const int* __restrict__ src, const int* __restrict__ dst,
                        const int* __restrict__ offs, int* __restrict__ cnt2,
                        int* __restrict__ csrc, int E, int EP) {
    int e = blockIdx.x * 256 + threadIdx.x;
    if (e >= EP) return;
    int sv, d;
    if (e < E) { sv = src[e]; d = dst[e]; }
    else       { sv = e - E;  d = sv; }
    int p = offs[d] + atomicAdd(&cnt2[d], 1);
    csrc[p] = sv;
}

// ---------------- L0 vector gemm (FIN=9), fp16 out ----------------
template <int FIN>
__global__ void gemm2_f16_k(const float* __restrict__ X,
                            const float* __restrict__ Wl, const float* __restrict__ bl,
                            const float* __restrict__ Wr, const float* __restrict__ br,
                            unsigned short* __restrict__ xl, unsigned short* __restrict__ xr,
                            int N, int HCT) {
    constexpr int RPT = 16;
    __shared__ float Xs[RPT][FIN];
    int tid  = threadIdx.x;
    int col  = blockIdx.y * 256 + tid;
    int row0 = blockIdx.x * RPT;
    for (int i = tid; i < RPT * FIN; i += 256) {
        int r = i / FIN, k = i % FIN;
        int gr = row0 + r;
        Xs[r][k] = (gr < N) ? X[(size_t)gr * FIN + k] : 0.f;
    }
    __syncthreads();
    float aL[RPT], aR[RPT];
    float b1 = bl[col], b2 = br[col];
#pragma unroll
    for (int r = 0; r < RPT; r++) { aL[r] = b1; aR[r] = b2; }
    for (int k = 0; k < FIN; k++) {
        float wl = Wl[(size_t)k * HCT + col];
        float wr = Wr[(size_t)k * HCT + col];
#pragma unroll
        for (int r = 0; r < RPT; r++) {
            float xv = Xs[r][k];
            aL[r] = fmaf(xv, wl, aL[r]);
            aR[r] = fmaf(xv, wr, aR[r]);
        }
    }
#pragma unroll
    for (int r = 0; r < RPT; r++) {
        int gr = row0 + r;
        if (gr < N) {
            xl[(size_t)gr * HCT + col] = __builtin_bit_cast(unsigned short, (f16)aL[r]);
            xr[(size_t)gr * HCT + col] = __builtin_bit_cast(unsigned short, (f16)aR[r]);
        }
    }
}

// ---------------- pack W (L1 and L2) into MFMA B-frag order, hi/lo ----------
__device__ __forceinline__ void pack_one(const float* Wl, const float* Wr,
                                         unsigned short* Wh, unsigned short* Wlo,
                                         int HCT, int t) {
    int j  = t & 7;
    int l  = (t >> 3) & 63;
    int ks = (t >> 9) & 1;
    int ct = t >> 10;
    int k  = ks * 32 + (l >> 4) * 8 + j;
    int cg = ct * 16 + (l & 15);
    float v = (cg < HCT) ? Wl[(size_t)k * HCT + cg] : Wr[(size_t)k * HCT + (cg - HCT)];
    unsigned short hi = f2bf(v);
    Wh[t]  = hi;
    Wlo[t] = f2bf(v - bf2f(hi));
}

__global__ void split_w2_k(const float* __restrict__ Wl1, const float* __restrict__ Wr1,
                           unsigned short* __restrict__ W1h, unsigned short* __restrict__ W1l,
                           const float* __restrict__ Wl2, const float* __restrict__ Wr2,
                           unsigned short* __restrict__ W2h, unsigned short* __restrict__ W2l) {
    int tid = blockIdx.x * 256 + threadIdx.x;
    if (tid < 32 * 1024) pack_one(Wl1, Wr1, W1h, W1l, 256, tid);
    else                 pack_one(Wl2, Wr2, W2h, W2l, 512, tid - 32 * 1024);
}

// ---------------- MFMA gemm: [N x 64] @ [64 x HCT] x2 -> fp16 ----------------
template <int CHUNKS>
__global__ void mfma_gemm_k(const unsigned short* __restrict__ Ahi,
                            const unsigned short* __restrict__ Alo,
                            const unsigned short* __restrict__ Wphi,
                            const unsigned short* __restrict__ Wplo,
                            const float* __restrict__ bl, const float* __restrict__ br,
                            unsigned short* __restrict__ xl, unsigned short* __restrict__ xr,
                            int N, int HCT) {
    __shared__ float lds[4][16][128];
    int tid = threadIdx.x;
    int w   = tid >> 6, l = tid & 63;
    int l15 = l & 15,  seg = l >> 4;
    int row  = blockIdx.x * 64 + w * 16 + l15;
    int arow = (row < N) ? row : (N - 1);

    bf16x8 a0h = *(const bf16x8*)(Ahi + (size_t)arow * 64 + seg * 8);
    bf16x8 a1h = *(const bf16x8*)(Ahi + (size_t)arow * 64 + 32 + seg * 8);
    bf16x8 a0l = *(const bf16x8*)(Alo + (size_t)arow * 64 + seg * 8);
    bf16x8 a1l = *(const bf16x8*)(Alo + (size_t)arow * 64 + 32 + seg * 8);

    for (int c = 0; c < CHUNKS; c++) {
        int mat   = (c * 128) / HCT;
        int mcol0 = (c * 128) % HCT;
        const float* bias = mat ? br : bl;
        unsigned short* out = mat ? xr : xl;
        f32x4 acc[8];
#pragma unroll
        for (int t = 0; t < 8; t++) {
            float bv = bias[mcol0 + t * 16 + l15];
            acc[t] = (f32x4){bv, bv, bv, bv};
        }
#pragma unroll
        for (int t = 0; t < 8; t++) {
            size_t ct = (size_t)(c * 8 + t);
            bf16x8 b0h = *(const bf16x8*)(Wphi + ((ct * 2    ) * 64 + l) * 8);
            bf16x8 b1h = *(const bf16x8*)(Wphi + ((ct * 2 + 1) * 64 + l) * 8);
            bf16x8 b0l = *(const bf16x8*)(Wplo + ((ct * 2    ) * 64 + l) * 8);
            bf16x8 b1l = *(const bf16x8*)(Wplo + ((ct * 2 + 1) * 64 + l) * 8);
            acc[t] = __builtin_amdgcn_mfma_f32_16x16x32_bf16(a0h, b0h, acc[t], 0, 0, 0);
            acc[t] = __builtin_amdgcn_mfma_f32_16x16x32_bf16(a1h, b1h, acc[t], 0, 0, 0);
            acc[t] = __builtin_amdgcn_mfma_f32_16x16x32_bf16(a0l, b0h, acc[t], 0, 0, 0);
            acc[t] = __builtin_amdgcn_mfma_f32_16x16x32_bf16(a1l, b1h, acc[t], 0, 0, 0);
            acc[t] = __builtin_amdgcn_mfma_f32_16x16x32_bf16(a0h, b0l, acc[t], 0, 0, 0);
            acc[t] = __builtin_amdgcn_mfma_f32_16x16x32_bf16(a1h, b1l, acc[t], 0, 0, 0);
        }
#pragma unroll
        for (int t = 0; t < 8; t++)
#pragma unroll
            for (int r = 0; r < 4; r++)
                lds[w][seg * 4 + r][t * 16 + l15] = acc[t][r];
#pragma unroll
        for (int r = 0; r < 16; r++) {
            int orow = blockIdx.x * 64 + w * 16 + r;
            if (orow < N) {
                float v0 = lds[w][r][2 * l];
                float v1 = lds[w][r][2 * l + 1];
                h2 hv = { (f16)v0, (f16)v1 };
                *(unsigned*)(out + (size_t)orow * HCT + mcol0 + 2 * l) =
                    __builtin_bit_cast(unsigned, hv);
            }
        }
    }
}

// ---------------- fused node pass: 2 edges per iteration ----------------
// OUT=0: write relu(res) as hi/lo bf16 split; OUT=1: fp32 out (no relu).
// acc accumulates w*a (a = xv+xr); epilogue: out = acc/s - xr per head.
template <int F, int OUT>
__global__ void node_fused_k(const unsigned short* __restrict__ xl,
                             const unsigned short* __restrict__ xr,
                             const float* __restrict__ att, const float* __restrict__ bias,
                             const int* __restrict__ offs, const int* __restrict__ csrc,
                             unsigned short* __restrict__ Yhi, unsigned short* __restrict__ Ylo,
                             float* __restrict__ out, int N) {
    constexpr int HCT = 64 * F;
    constexpr int NW  = F / 2;
    int wv   = blockIdx.x * 4 + (threadIdx.x >> 6);
    int lane = threadIdx.x & 63;
    if (wv >= N) return;

    h2 xrh[NW], ath[NW];
    {
        const unsigned* xp = (const unsigned*)(xr + (size_t)wv * HCT + lane * F);
#pragma unroll
        for (int i = 0; i < NW; i++) {
            xrh[i] = __builtin_bit_cast(h2, xp[i]);
            ath[i] = h2{ (f16)att[lane * F + 2 * i], (f16)att[lane * F + 2 * i + 1] };
        }
    }

    int o0 = offs[wv], o1 = offs[wv + 1];
    float m = -1e30f, s = 0.f;
    f2 acc[NW];
#pragma unroll
    for (int i = 0; i < NW; i++) acc[i] = f2{0.f, 0.f};

    int j = o0;
    if ((o1 - o0) & 1) {                     // odd tail first: exact single edge
        int sn = csrc[j];
        const unsigned* xp = (const unsigned*)(xl + (size_t)sn * HCT + lane * F);
        h2 a[NW];
        float p1 = 0.f, p2 = 0.f;
#pragma unroll
        for (int i = 0; i < NW; i++) {
            h2 xv = __builtin_bit_cast(h2, xp[i]);
            a[i] = xv + xrh[i];
            unsigned au = __builtin_bit_cast(unsigned, a[i]) & 0x7FFF7FFFu;
            p1 = __builtin_amdgcn_fdot2(ath[i], a[i], p1, false);
            p2 = __builtin_amdgcn_fdot2(ath[i], __builtin_bit_cast(h2, au), p2, false);
        }
        float p = fmaf(0.6f, p1, 0.4f * p2);
        p += __shfl_xor(p, 1, 64);
        p += __shfl_xor(p, 2, 64);
        p += __shfl_xor(p, 4, 64);
        p += __shfl_xor(p, 8, 64);
        float nm = fmaxf(m, p);
        float r  = __expf(m - nm);
        float w  = __expf(p - nm);
        s = fmaf(s, r, w);
        f2 r2 = {r, r}, w2 = {w, w};
#pragma unroll
        for (int i = 0; i < NW; i++) {
            f2 af = __builtin_convertvector(a[i], f2);
            acc[i] = __builtin_elementwise_fma(acc[i], r2, af * w2);
        }
        m = nm;
        j++;
    }

    for (; j < o1; j += 2) {                 // pair loop: 2 gathers in flight
        int s0 = csrc[j], s1 = csrc[j + 1];
        const unsigned* xp0 = (const unsigned*)(xl + (size_t)s0 * HCT + lane * F);
        const unsigned* xp1 = (const unsigned*)(xl + (size_t)s1 * HCT + lane * F);
        unsigned r0[NW], r1[NW];
#pragma unroll
        for (int i = 0; i < NW; i++) r0[i] = xp0[i];
#pragma unroll
        for (int i = 0; i < NW; i++) r1[i] = xp1[i];
        h2 a0[NW], a1[NW];
        float p1a = 0.f, p2a = 0.f, p1b = 0.f, p2b = 0.f;
#pragma unroll
        for (int i = 0; i < NW; i++) {
            h2 xv0 = __builtin_bit_cast(h2, r0[i]);
            a0[i] = xv0 + xrh[i];
            unsigned au0 = __builtin_bit_cast(unsigned, a0[i]) & 0x7FFF7FFFu;
            p1a = __builtin_amdgcn_fdot2(ath[i], a0[i], p1a, false);
            p2a = __builtin_amdgcn_fdot2(ath[i], __builtin_bit_cast(h2, au0), p2a, false);
            h2 xv1 = __builtin_bit_cast(h2, r1[i]);
            a1[i] = xv1 + xrh[i];
            unsigned au1 = __builtin_bit_cast(unsigned, a1[i]) & 0x7FFF7FFFu;
            p1b = __builtin_amdgcn_fdot2(ath[i], a1[i], p1b, false);
            p2b = __builtin_amdgcn_fdot2(ath[i], __builtin_bit_cast(h2, au1), p2b, false);
        }
        float pa = fmaf(0.6f, p1a, 0.4f * p2a);
        float pb = fmaf(0.6f, p1b, 0.4f * p2b);
        pa += __shfl_xor(pa, 1, 64);
        pa += __shfl_xor(pa, 2, 64);
        pa += __shfl_xor(pa, 4, 64);
        pa += __shfl_xor(pa, 8, 64);
        pb += __shfl_xor(pb, 1, 64);
        pb += __shfl_xor(pb, 2, 64);
        pb += __shfl_xor(pb, 4, 64);
        pb += __shfl_xor(pb, 8, 64);
        if (__any(fmaxf(pa, pb) > m + 20.f)) {       // rare: exact sequential
            {
                float nm = fmaxf(m, pa);
                float r  = __expf(m - nm);
                float w  = __expf(pa - nm);
                s = fmaf(s, r, w);
                f2 r2 = {r, r}, w2 = {w, w};
#pragma unroll
                for (int i = 0; i < NW; i++) {
                    f2 af = __builtin_convertvector(a0[i], f2);
                    acc[i] = __builtin_elementwise_fma(acc[i], r2, af * w2);
                }
                m = nm;
            }
            {
                float nm = fmaxf(m, pb);
                float r  = __expf(m - nm);
                float w  = __expf(pb - nm);
                s = fmaf(s, r, w);
                f2 r2 = {r, r}, w2 = {w, w};
#pragma unroll
                for (int i = 0; i < NW; i++) {
                    f2 af = __builtin_convertvector(a1[i], f2);
                    acc[i] = __builtin_elementwise_fma(acc[i], r2, af * w2);
                }
                m = nm;
            }
        } else {                                      // common: both <= m+20
            float wa = __expf(pa - m);
            float wb = __expf(pb - m);
            s += wa + wb;
            f2 wa2 = {wa, wa}, wb2 = {wb, wb};
#pragma unroll
            for (int i = 0; i < NW; i++) {
                f2 af0 = __builtin_convertvector(a0[i], f2);
                f2 af1 = __builtin_convertvector(a1[i], f2);
                acc[i] = __builtin_elementwise_fma(af0, wa2, acc[i]);
                acc[i] = __builtin_elementwise_fma(af1, wb2, acc[i]);
            }
        }
    }

    float inv = 1.f / s;
    f2 inv2 = {inv, inv};
    float val[F];
#pragma unroll
    for (int i = 0; i < NW; i++) {
        f2 xrf = __builtin_convertvector(xrh[i], f2);
        f2 v = __builtin_elementwise_fma(acc[i], inv2, -xrf);   // acc/s - xr
        val[2 * i] = v.x; val[2 * i + 1] = v.y;
    }
#pragma unroll
    for (int i = 0; i < F; i++) {                 // sum the 4 heads
        val[i] += __shfl_xor(val[i], 16, 64);
        val[i] += __shfl_xor(val[i], 32, 64);
    }
    if (lane < 16) {
        if (OUT == 0) {
            unsigned short h[F], lo[F];
#pragma unroll
            for (int i = 0; i < F; i++) {
                float v = fmaf(val[i], 0.25f, bias[lane * F + i]);
                v = fmaxf(v, 0.f);
                h[i] = f2bf(v);
                lo[i] = f2bf(v - bf2f(h[i]));
            }
            size_t base = (size_t)wv * (16 * F) + lane * F;
#pragma unroll
            for (int i = 0; i < F / 2; i++) {
                ((unsigned*)(Yhi + base))[i] = (unsigned)h[2 * i] | ((unsigned)h[2 * i + 1] << 16);
                ((unsigned*)(Ylo + base))[i] = (unsigned)lo[2 * i] | ((unsigned)lo[2 * i + 1] << 16);
            }
        } else {
            float* op = out + (size_t)wv * (16 * F) + lane * F;
#pragma unroll
            for (int i = 0; i < F; i++)
                op[i] = fmaf(val[i], 0.25f, bias[lane * F + i]);
        }
    }
}

// ---------------------------------------------------------------------------

static inline size_t align256(size_t x) { return (x + 255) & ~(size_t)255; }

extern "C" void kernel_launch(void* const* d_in, const int* in_sizes, int n_in,
                              void* d_out, int out_size, void* d_ws, size_t ws_size,
                              hipStream_t stream) {
    const float* x  = (const float*)d_in[0];
    const int*   ei = (const int*)d_in[1];
    const int N  = in_sizes[0] / 9;
    const int E  = in_sizes[1] / 2;
    const int EP = E + N;
    const int* src = ei;
    const int* dst = ei + E;

    const float *Wl[3], *bl[3], *Wr[3], *br[3], *att[3], *bb[3];
    for (int i = 0; i < 3; i++) {
        Wl[i]  = (const float*)d_in[2 + 6 * i];
        bl[i]  = (const float*)d_in[3 + 6 * i];
        Wr[i]  = (const float*)d_in[4 + 6 * i];
        br[i]  = (const float*)d_in[5 + 6 * i];
        att[i] = (const float*)d_in[6 + 6 * i];
        bb[i]  = (const float*)d_in[7 + 6 * i];
    }

    // workspace layout (~131 MB)
    char* w = (char*)d_ws;
    unsigned short* xl  = (unsigned short*)w; w += align256((size_t)N * 512 * 2);
    unsigned short* xr  = (unsigned short*)w; w += align256((size_t)N * 512 * 2);
    unsigned short* A1h = (unsigned short*)w; w += align256((size_t)N * 64 * 2);
    unsigned short* A1l = (unsigned short*)w; w += align256((size_t)N * 64 * 2);
    unsigned short* A2h = (unsigned short*)w; w += align256((size_t)N * 64 * 2);
    unsigned short* A2l = (unsigned short*)w; w += align256((size_t)N * 64 * 2);
    int* offs   = (int*)w;  w += align256((size_t)(N + 1) * 4);
    int* cnt    = (int*)w;  w += align256((size_t)(2 * N) * 4);   // cnt + cnt2
    int* csrc   = (int*)w;  w += align256((size_t)EP * 4);
    int* partial = (int*)w; w += 4096;
    unsigned short* Wp1h = (unsigned short*)w; w += align256((size_t)32 * 1024 * 2);
    unsigned short* Wp1l = (unsigned short*)w; w += align256((size_t)32 * 1024 * 2);
    unsigned short* Wp2h = (unsigned short*)w; w += align256((size_t)64 * 1024 * 2);
    unsigned short* Wp2l = (unsigned short*)w; w += align256((size_t)64 * 1024 * 2);
    int* cnt2 = cnt + N;

    // ---- CSR build over dst (5 dispatches) ----
    zero_int_k<<<(2 * N + 255) / 256, 256, 0, stream>>>(cnt, 2 * N);
    count_k<<<(EP + 255) / 256, 256, 0, stream>>>(dst, cnt, E, EP);
    int nb = (N + 1023) / 1024;
    scan1_k<<<nb, 1024, 0, stream>>>(cnt, offs, partial, N);
    scan23_k<<<nb, 1024, 0, stream>>>(offs, partial, N);
    fill2_k<<<(EP + 255) / 256, 256, 0, stream>>>(src, dst, offs, cnt2, csrc, E, EP);

    // ---- pack L1/L2 weights (one dispatch) ----
    split_w2_k<<<(96 * 1024) / 256, 256, 0, stream>>>(
        Wl[1], Wr[1], Wp1h, Wp1l, Wl[2], Wr[2], Wp2h, Wp2l);

    const int nodeBlocks = (N + 3) / 4;
    const int gemmBlocks = (N + 63) / 64;

    // ---- layer 0: vector gemm + node pass -> A1 hi/lo split ----
    dim3 g1((N + 15) / 16, 1);
    gemm2_f16_k<9><<<g1, 256, 0, stream>>>(
        x, Wl[0], bl[0], Wr[0], br[0], xl, xr, N, 256);
    node_fused_k<4, 0><<<nodeBlocks, 256, 0, stream>>>(
        xl, xr, att[0], bb[0], offs, csrc, A1h, A1l, nullptr, N);

    // ---- layer 1: MFMA gemm + node pass -> A2 hi/lo split ----
    mfma_gemm_k<4><<<gemmBlocks, 256, 0, stream>>>(
        A1h, A1l, Wp1h, Wp1l, bl[1], br[1], xl, xr, N, 256);
    node_fused_k<4, 0><<<nodeBlocks, 256, 0, stream>>>(
        xl, xr, att[1], bb[1], offs, csrc, A2h, A2l, nullptr, N);

    // ---- layer 2: MFMA gemm + node pass -> fp32 d_out ----
    mfma_gemm_k<8><<<gemmBlocks, 256, 0, stream>>>(
        A2h, A2l, Wp2h, Wp2l, bl[2], br[2], xl, xr, N, 512);
    node_fused_k<8, 1><<<nodeBlocks, 256, 0, stream>>>(
        xl, xr, att[2], bb[2], offs, csrc, nullptr, nullptr, (float*)d_out, N);
}